// Round 1
// baseline (7108.764 us; speedup 1.0000x reference)
//
#include <hip/hip_runtime.h>
#include <hip/hip_bf16.h>
#include <math.h>

#define BB 4
#define SS 1024
#define DD 768
#define HH 12
#define NLAYER 6
#define DHH 64
#define DFF 3072
#define D3 2304
#define LN_EPS 1e-5f

// ---------------- embedding: h = wte[ids] + wte_rf[rf] + wpe[s] ----------------
__global__ __launch_bounds__(256) void embed_kernel(
    const int* __restrict__ ids, const int* __restrict__ rf,
    const float* __restrict__ wte, const float* __restrict__ wte_rf,
    const float* __restrict__ wpe, float* __restrict__ h)
{
  int idx = blockIdx.x * 256 + threadIdx.x;        // float4 index over T*D/4
  int token = idx / (DD / 4);
  int c4 = (idx % (DD / 4)) * 4;
  int s = token % SS;
  int id  = ids[token];
  int rid = rf[token];
  float4 a = *(const float4*)(wte    + (size_t)id  * DD + c4);
  float4 b = *(const float4*)(wte_rf + (size_t)rid * DD + c4);
  float4 c = *(const float4*)(wpe    + (size_t)s   * DD + c4);
  float4 o;
  o.x = a.x + b.x + c.x;
  o.y = a.y + b.y + c.y;
  o.z = a.z + b.z + c.z;
  o.w = a.w + b.w + c.w;
  *(float4*)(h + (size_t)token * DD + c4) = o;
}

// ---------------- LayerNorm: one block (192 threads) per row of 768 ----------------
__global__ __launch_bounds__(192) void ln_kernel(
    const float* __restrict__ x, const float* __restrict__ g,
    const float* __restrict__ bb, float* __restrict__ y)
{
  __shared__ float red[2][3];
  int row = blockIdx.x;
  int t = threadIdx.x;
  const float* xr = x + (size_t)row * DD;
  float4 v = *(const float4*)(xr + t * 4);
  float s  = v.x + v.y + v.z + v.w;
  float sq = v.x * v.x + v.y * v.y + v.z * v.z + v.w * v.w;
  #pragma unroll
  for (int off = 32; off > 0; off >>= 1) {
    s  += __shfl_down(s, off);
    sq += __shfl_down(sq, off);
  }
  int wave = t >> 6, lane = t & 63;
  if (lane == 0) { red[0][wave] = s; red[1][wave] = sq; }
  __syncthreads();
  s  = red[0][0] + red[0][1] + red[0][2];
  sq = red[1][0] + red[1][1] + red[1][2];
  float mu   = s * (1.0f / DD);
  float var  = sq * (1.0f / DD) - mu * mu;
  float rstd = rsqrtf(var + LN_EPS);
  float4 gv = *(const float4*)(g  + t * 4);
  float4 bv = *(const float4*)(bb + t * 4);
  float4 o;
  o.x = (v.x - mu) * rstd * gv.x + bv.x;
  o.y = (v.y - mu) * rstd * gv.y + bv.y;
  o.z = (v.z - mu) * rstd * gv.z + bv.z;
  o.w = (v.w - mu) * rstd * gv.w + bv.w;
  *(float4*)(y + (size_t)row * DD + t * 4) = o;
}

__device__ __forceinline__ float gelu_f(float x) {
  float x3 = x * x * x;
  return 0.5f * x * (1.0f + tanhf(0.7978845608028654f * (x + 0.044715f * x3)));
}

// ---------------- GEMM: C[M,N] = A[M,K] @ W[K,N] + bias (+residual / gelu) -------
// mode 0: plain   mode 1: += R   mode 2: gelu
__global__ __launch_bounds__(256) void gemm_kernel(
    const float* __restrict__ A, const float* __restrict__ W,
    const float* __restrict__ bias, const float* __restrict__ R,
    float* __restrict__ C, int M, int N, int K, int mode)
{
  __shared__ float As[16][68];
  __shared__ float Ws[16][68];
  const int t  = threadIdx.x;
  const int tx = t & 15, ty = t >> 4;
  const int bm = blockIdx.y * 64, bn = blockIdx.x * 64;
  const int r0 = ty * 4, c0 = tx * 4;
  float acc[4][4] = {{0.f}};
  const int arow = t >> 2, ak4 = (t & 3) * 4;
  const int wrow = t >> 4, wn4 = (t & 15) * 4;
  const float* Ap = A + (size_t)(bm + arow) * K + ak4;
  const float* Wp = W + (size_t)wrow * N + bn + wn4;

  for (int k0 = 0; k0 < K; k0 += 16) {
    float4 av = *(const float4*)(Ap + k0);
    As[ak4 + 0][arow] = av.x;
    As[ak4 + 1][arow] = av.y;
    As[ak4 + 2][arow] = av.z;
    As[ak4 + 3][arow] = av.w;
    *(float4*)(&Ws[wrow][wn4]) = *(const float4*)(Wp + (size_t)k0 * N);
    __syncthreads();
    #pragma unroll
    for (int kk = 0; kk < 16; ++kk) {
      float av4[4], bv4[4];
      #pragma unroll
      for (int i = 0; i < 4; ++i) av4[i] = As[kk][r0 + i];
      #pragma unroll
      for (int j = 0; j < 4; ++j) bv4[j] = Ws[kk][c0 + j];
      #pragma unroll
      for (int i = 0; i < 4; ++i)
        #pragma unroll
        for (int j = 0; j < 4; ++j)
          acc[i][j] = fmaf(av4[i], bv4[j], acc[i][j]);
    }
    __syncthreads();
  }

  #pragma unroll
  for (int i = 0; i < 4; ++i) {
    int row = bm + r0 + i;
    float o0 = acc[i][0] + bias[bn + c0 + 0];
    float o1 = acc[i][1] + bias[bn + c0 + 1];
    float o2 = acc[i][2] + bias[bn + c0 + 2];
    float o3 = acc[i][3] + bias[bn + c0 + 3];
    if (mode == 1) {
      float4 rv = *(const float4*)(R + (size_t)row * N + bn + c0);
      o0 += rv.x; o1 += rv.y; o2 += rv.z; o3 += rv.w;
    } else if (mode == 2) {
      o0 = gelu_f(o0); o1 = gelu_f(o1); o2 = gelu_f(o2); o3 = gelu_f(o3);
    }
    float4 ov = {o0, o1, o2, o3};
    *(float4*)(C + (size_t)row * N + bn + c0) = ov;
  }
}

// ---------------- Flash attention (fp32, causal, 64x64 tiles) ----------------
// qkv layout [B*S, 3D]; q cols [h*64, +64), k cols D+h*64, v cols 2D+h*64.
__global__ __launch_bounds__(256) void attn_kernel(
    const float* __restrict__ qkv, float* __restrict__ o)
{
  __shared__ float Qs[64][65], Ks[64][65], Vs[64][65], Ps[64][65];
  __shared__ float m_s[64], l_s[64];
  const int t  = threadIdx.x;
  const int qt = blockIdx.x;
  const int bh = blockIdx.y;
  const int b  = bh / HH, hd = bh % HH;
  const float* qbase = qkv + (size_t)b * SS * D3 + hd * DHH;
  const float* kbase = qbase + DD;
  const float* vbase = qbase + 2 * DD;

  #pragma unroll
  for (int jj = 0; jj < 4; ++jj) {
    int idx = t + 256 * jj;
    int r = idx >> 4, c4 = (idx & 15) * 4;
    float4 v = *(const float4*)(qbase + (size_t)(qt * 64 + r) * D3 + c4);
    Qs[r][c4 + 0] = v.x * 0.125f;
    Qs[r][c4 + 1] = v.y * 0.125f;
    Qs[r][c4 + 2] = v.z * 0.125f;
    Qs[r][c4 + 3] = v.w * 0.125f;
  }
  if (t < 64) { m_s[t] = -1e30f; l_s[t] = 0.0f; }
  const int tx = t & 15, ty = t >> 4;
  const int r0 = ty * 4, c0 = tx * 4;
  float oacc[4][4] = {{0.f}};
  __syncthreads();

  for (int kt = 0; kt <= qt; ++kt) {
    #pragma unroll
    for (int jj = 0; jj < 4; ++jj) {
      int idx = t + 256 * jj;
      int r = idx >> 4, c4 = (idx & 15) * 4;
      float4 kv = *(const float4*)(kbase + (size_t)(kt * 64 + r) * D3 + c4);
      float4 vv = *(const float4*)(vbase + (size_t)(kt * 64 + r) * D3 + c4);
      Ks[r][c4 + 0] = kv.x; Ks[r][c4 + 1] = kv.y;
      Ks[r][c4 + 2] = kv.z; Ks[r][c4 + 3] = kv.w;
      Vs[r][c4 + 0] = vv.x; Vs[r][c4 + 1] = vv.y;
      Vs[r][c4 + 2] = vv.z; Vs[r][c4 + 3] = vv.w;
    }
    __syncthreads();

    float sc[4][4] = {{0.f}};
    for (int d = 0; d < 64; ++d) {
      float qa[4], kb[4];
      #pragma unroll
      for (int i = 0; i < 4; ++i) qa[i] = Qs[r0 + i][d];
      #pragma unroll
      for (int j = 0; j < 4; ++j) kb[j] = Ks[c0 + j][d];
      #pragma unroll
      for (int i = 0; i < 4; ++i)
        #pragma unroll
        for (int j = 0; j < 4; ++j)
          sc[i][j] = fmaf(qa[i], kb[j], sc[i][j]);
    }
    if (kt == qt) {
      #pragma unroll
      for (int i = 0; i < 4; ++i)
        #pragma unroll
        for (int j = 0; j < 4; ++j)
          if (c0 + j > r0 + i) sc[i][j] = -1e30f;
    }
    #pragma unroll
    for (int i = 0; i < 4; ++i) {
      float mx = fmaxf(fmaxf(sc[i][0], sc[i][1]), fmaxf(sc[i][2], sc[i][3]));
      #pragma unroll
      for (int off = 1; off < 16; off <<= 1) mx = fmaxf(mx, __shfl_xor(mx, off));
      float mold = m_s[r0 + i];
      float mnew = fmaxf(mold, mx);
      float rsum = 0.f;
      #pragma unroll
      for (int j = 0; j < 4; ++j) {
        float p = __expf(sc[i][j] - mnew);
        Ps[r0 + i][c0 + j] = p;
        rsum += p;
      }
      #pragma unroll
      for (int off = 1; off < 16; off <<= 1) rsum += __shfl_xor(rsum, off);
      float alpha = __expf(mold - mnew);
      #pragma unroll
      for (int j = 0; j < 4; ++j) oacc[i][j] *= alpha;
      if (tx == 0) { m_s[r0 + i] = mnew; l_s[r0 + i] = l_s[r0 + i] * alpha + rsum; }
    }
    __syncthreads();

    for (int c = 0; c < 64; ++c) {
      float pa[4], vb[4];
      #pragma unroll
      for (int i = 0; i < 4; ++i) pa[i] = Ps[r0 + i][c];
      #pragma unroll
      for (int j = 0; j < 4; ++j) vb[j] = Vs[c][c0 + j];
      #pragma unroll
      for (int i = 0; i < 4; ++i)
        #pragma unroll
        for (int j = 0; j < 4; ++j)
          oacc[i][j] = fmaf(pa[i], vb[j], oacc[i][j]);
    }
    __syncthreads();
  }

  #pragma unroll
  for (int i = 0; i < 4; ++i) {
    float linv = 1.0f / l_s[r0 + i];
    float4 ov = {oacc[i][0] * linv, oacc[i][1] * linv,
                 oacc[i][2] * linv, oacc[i][3] * linv};
    *(float4*)(o + ((size_t)b * SS + qt * 64 + r0 + i) * DD + hd * DHH + c0) = ov;
  }
}

extern "C" void kernel_launch(void* const* d_in, const int* in_sizes, int n_in,
                              void* d_out, int out_size, void* d_ws, size_t ws_size,
                              hipStream_t stream)
{
  (void)in_sizes; (void)n_in; (void)out_size; (void)ws_size;
  const int*   ids    = (const int*)d_in[0];
  const int*   rfids  = (const int*)d_in[1];
  const float* wte    = (const float*)d_in[2];
  const float* wte_rf = (const float*)d_in[3];
  const float* wpe    = (const float*)d_in[4];
  const float* ln1_g  = (const float*)d_in[5];
  const float* ln1_b  = (const float*)d_in[6];
  const float* attn_w = (const float*)d_in[7];
  const float* attn_b = (const float*)d_in[8];
  const float* proj_w = (const float*)d_in[9];
  const float* proj_b = (const float*)d_in[10];
  const float* ln2_g  = (const float*)d_in[11];
  const float* ln2_b  = (const float*)d_in[12];
  const float* fc_w   = (const float*)d_in[13];
  const float* fc_b   = (const float*)d_in[14];
  const float* fc2_w  = (const float*)d_in[15];
  const float* fc2_b  = (const float*)d_in[16];
  const float* lnf_g  = (const float*)d_in[17];
  const float* lnf_b  = (const float*)d_in[18];

  const int T = BB * SS;  // 4096 tokens
  float* ws   = (float*)d_ws;
  float* h    = ws;                       // T*D
  float* a    = h    + (size_t)T * DD;    // T*D
  float* qkvb = a    + (size_t)T * DD;    // T*3D
  float* att  = qkvb + (size_t)T * D3;    // T*D
  float* ff   = qkvb;                     // T*DF, aliases dead qkv+att region

  embed_kernel<<<dim3((T * DD / 4) / 256), 256, 0, stream>>>(ids, rfids, wte, wte_rf, wpe, h);

  for (int l = 0; l < NLAYER; ++l) {
    ln_kernel<<<T, 192, 0, stream>>>(h, ln1_g + (size_t)l * DD, ln1_b + (size_t)l * DD, a);
    gemm_kernel<<<dim3(D3 / 64, T / 64), 256, 0, stream>>>(
        a, attn_w + (size_t)l * DD * D3, attn_b + (size_t)l * D3, nullptr, qkvb, T, D3, DD, 0);
    attn_kernel<<<dim3(SS / 64, BB * HH), 256, 0, stream>>>(qkvb, att);
    gemm_kernel<<<dim3(DD / 64, T / 64), 256, 0, stream>>>(
        att, proj_w + (size_t)l * DD * DD, proj_b + (size_t)l * DD, h, h, T, DD, DD, 1);
    ln_kernel<<<T, 192, 0, stream>>>(h, ln2_g + (size_t)l * DD, ln2_b + (size_t)l * DD, a);
    gemm_kernel<<<dim3(DFF / 64, T / 64), 256, 0, stream>>>(
        a, fc_w + (size_t)l * DD * DFF, fc_b + (size_t)l * DFF, nullptr, ff, T, DFF, DD, 2);
    gemm_kernel<<<dim3(DD / 64, T / 64), 256, 0, stream>>>(
        ff, fc2_w + (size_t)l * DFF * DD, fc2_b + (size_t)l * DD, h, h, T, DD, DFF, 1);
  }
  ln_kernel<<<T, 192, 0, stream>>>(h, lnf_g, lnf_b, (float*)d_out);
}

// Round 3
// 3819.398 us; speedup vs baseline: 1.8612x; 1.8612x over previous
//
#include <hip/hip_runtime.h>
#include <hip/hip_bf16.h>
#include <math.h>

#define BB 4
#define SS 1024
#define DD 768
#define HH 12
#define NLAYER 6
#define DHH 64
#define DFF 3072
#define D3 2304
#define LN_EPS 1e-5f

typedef __hip_bfloat16 bf16;
typedef short bf16x8 __attribute__((ext_vector_type(8)));
typedef float f32x4 __attribute__((ext_vector_type(4)));

__device__ __forceinline__ void gload_lds16(const void* g, void* l) {
  __builtin_amdgcn_global_load_lds(
      (const __attribute__((address_space(1))) void*)g,
      (__attribute__((address_space(3))) void*)l, 16, 0, 0);
}

__device__ __forceinline__ unsigned short f2bf_bits(float x) {
  bf16 h = __float2bfloat16(x);
  union { bf16 h; unsigned short u; } c; c.h = h; return c.u;
}

// ---------------- embedding: h = wte[ids] + wte_rf[rf] + wpe[s] ----------------
__global__ __launch_bounds__(256) void embed_kernel(
    const int* __restrict__ ids, const int* __restrict__ rf,
    const float* __restrict__ wte, const float* __restrict__ wte_rf,
    const float* __restrict__ wpe, float* __restrict__ h)
{
  int idx = blockIdx.x * 256 + threadIdx.x;
  int token = idx / (DD / 4);
  int c4 = (idx % (DD / 4)) * 4;
  int s = token % SS;
  int id  = ids[token];
  int rid = rf[token];
  float4 a = *(const float4*)(wte    + (size_t)id  * DD + c4);
  float4 b = *(const float4*)(wte_rf + (size_t)rid * DD + c4);
  float4 c = *(const float4*)(wpe    + (size_t)s   * DD + c4);
  float4 o;
  o.x = a.x + b.x + c.x;
  o.y = a.y + b.y + c.y;
  o.z = a.z + b.z + c.z;
  o.w = a.w + b.w + c.w;
  *(float4*)(h + (size_t)token * DD + c4) = o;
}

// ---------------- weight transpose+cast: W[K][N] fp32 -> Wt[N][K] bf16 ----------
__global__ __launch_bounds__(256) void transpose_cast(
    const float* __restrict__ W, bf16* __restrict__ Wt, int K, int N)
{
  __shared__ float tile[32][33];
  int n0 = blockIdx.x * 32, k0 = blockIdx.y * 32;
  int tx = threadIdx.x & 31, ty = threadIdx.x >> 5;
  #pragma unroll
  for (int i = 0; i < 4; ++i)
    tile[ty + 8 * i][tx] = W[(size_t)(k0 + ty + 8 * i) * N + n0 + tx];
  __syncthreads();
  #pragma unroll
  for (int i = 0; i < 4; ++i)
    Wt[(size_t)(n0 + ty + 8 * i) * K + k0 + tx] = __float2bfloat16(tile[tx][ty + 8 * i]);
}

// ---------------- LayerNorm: one block (192 threads) per row of 768 ----------------
template <typename OutT>
__global__ __launch_bounds__(192) void ln_kernel(
    const float* __restrict__ x, const float* __restrict__ g,
    const float* __restrict__ bb, OutT* __restrict__ y)
{
  __shared__ float red[2][3];
  int row = blockIdx.x;
  int t = threadIdx.x;
  const float* xr = x + (size_t)row * DD;
  float4 v = *(const float4*)(xr + t * 4);
  float s  = v.x + v.y + v.z + v.w;
  float sq = v.x * v.x + v.y * v.y + v.z * v.z + v.w * v.w;
  #pragma unroll
  for (int off = 32; off > 0; off >>= 1) {
    s  += __shfl_down(s, off);
    sq += __shfl_down(sq, off);
  }
  int wave = t >> 6, lane = t & 63;
  if (lane == 0) { red[0][wave] = s; red[1][wave] = sq; }
  __syncthreads();
  s  = red[0][0] + red[0][1] + red[0][2];
  sq = red[1][0] + red[1][1] + red[1][2];
  float mu   = s * (1.0f / DD);
  float var  = sq * (1.0f / DD) - mu * mu;
  float rstd = rsqrtf(var + LN_EPS);
  float4 gv = *(const float4*)(g  + t * 4);
  float4 bv = *(const float4*)(bb + t * 4);
  float o0 = (v.x - mu) * rstd * gv.x + bv.x;
  float o1 = (v.y - mu) * rstd * gv.y + bv.y;
  float o2 = (v.z - mu) * rstd * gv.z + bv.z;
  float o3 = (v.w - mu) * rstd * gv.w + bv.w;
  if constexpr (sizeof(OutT) == 4) {
    float4 o = {o0, o1, o2, o3};
    *(float4*)((float*)y + (size_t)row * DD + t * 4) = o;
  } else {
    ushort4 o = {f2bf_bits(o0), f2bf_bits(o1), f2bf_bits(o2), f2bf_bits(o3)};
    *(ushort4*)((unsigned short*)y + (size_t)row * DD + t * 4) = o;
  }
}

__device__ __forceinline__ float gelu_f(float x) {
  float x3 = x * x * x;
  return 0.5f * x * (1.0f + tanhf(0.7978845608028654f * (x + 0.044715f * x3)));
}

// ---------------- bf16 MFMA GEMM: C[M,N] = A[M,K] @ Wt[N,K]^T + bias -------------
// m97 structure: 128x128 tile, BK=32, 4 waves (2x2), 16 mfma_16x16x32 per K-step.
// LDS interleaved [k8][row][8]: global_load_lds dest is linear (chunk c -> byte
// c*16) and fragment ds_read_b128 is K-contiguous.
// MODE 0: +bias   MODE 1: +bias+R(fp32)   MODE 2: gelu(+bias)
template <int MODE, typename OutT>
__global__ __launch_bounds__(256) void gemm_bf16(
    const bf16* __restrict__ A,   // [M][K]
    const bf16* __restrict__ Wt,  // [N][K]
    const float* __restrict__ bias,
    const float* __restrict__ R,
    OutT* __restrict__ C, int M, int N, int K)
{
  __shared__ alignas(16) unsigned short As[4][128][8];
  __shared__ alignas(16) unsigned short Bs[4][128][8];
  const int t = threadIdx.x;
  const int lane = t & 63, wid = t >> 6;
  const int wr = wid >> 1, wc = wid & 1;
  const int bm = blockIdx.y * 128, bn = blockIdx.x * 128;

  f32x4 acc[4][4] = {};

  // staging: chunk c (16B) -> k8 = c>>7, row = c&127; LDS byte offset = c*16
  const int c0 = t, c1 = t + 256;
  const unsigned short* Ag0 = (const unsigned short*)A + (size_t)(bm + (c0 & 127)) * K + (c0 >> 7) * 8;
  const unsigned short* Ag1 = (const unsigned short*)A + (size_t)(bm + (c1 & 127)) * K + (c1 >> 7) * 8;
  const unsigned short* Bg0 = (const unsigned short*)Wt + (size_t)(bn + (c0 & 127)) * K + (c0 >> 7) * 8;
  const unsigned short* Bg1 = (const unsigned short*)Wt + (size_t)(bn + (c1 & 127)) * K + (c1 >> 7) * 8;
  char* AsB = (char*)As;
  char* BsB = (char*)Bs;

  // fragment read offsets (bytes): (lane>>4)*2048 + row*16
  const int abase = (lane >> 4) * 2048 + (wr * 64 + (lane & 15)) * 16;
  const int bbase = (lane >> 4) * 2048 + (wc * 64 + (lane & 15)) * 16;

  for (int k0 = 0; k0 < K; k0 += 32) {
    gload_lds16(Ag0 + k0, AsB + c0 * 16);
    gload_lds16(Ag1 + k0, AsB + c1 * 16);
    gload_lds16(Bg0 + k0, BsB + c0 * 16);
    gload_lds16(Bg1 + k0, BsB + c1 * 16);
    __syncthreads();

    bf16x8 a[4], b[4];
    #pragma unroll
    for (int m = 0; m < 4; ++m) a[m] = *(const bf16x8*)(AsB + abase + m * 256);
    #pragma unroll
    for (int n = 0; n < 4; ++n) b[n] = *(const bf16x8*)(BsB + bbase + n * 256);
    #pragma unroll
    for (int m = 0; m < 4; ++m)
      #pragma unroll
      for (int n = 0; n < 4; ++n)
        acc[m][n] = __builtin_amdgcn_mfma_f32_16x16x32_bf16(a[m], b[n], acc[m][n], 0, 0, 0);
    __syncthreads();
  }

  // epilogue: C/D layout col=lane&15, row=(lane>>4)*4+reg  [m89-verified]
  const int colg = lane & 15, rowg = (lane >> 4) * 4;
  #pragma unroll
  for (int m = 0; m < 4; ++m) {
    #pragma unroll
    for (int n = 0; n < 4; ++n) {
      int col = bn + wc * 64 + n * 16 + colg;
      float bv = bias[col];
      #pragma unroll
      for (int r = 0; r < 4; ++r) {
        int row = bm + wr * 64 + m * 16 + rowg + r;
        float v = acc[m][n][r] + bv;
        if constexpr (MODE == 1) v += R[(size_t)row * N + col];
        if constexpr (MODE == 2) v = gelu_f(v);
        if constexpr (sizeof(OutT) == 4) ((float*)C)[(size_t)row * N + col] = v;
        else ((bf16*)C)[(size_t)row * N + col] = __float2bfloat16(v);
      }
    }
  }
}

// ---------------- Flash attention (fp32, causal, 64x64 tiles) ----------------
// qkv layout [B*S, 3D]; q cols [h*64, +64), k cols D+h*64, v cols 2D+h*64.
__global__ __launch_bounds__(256) void attn_kernel(
    const float* __restrict__ qkv, bf16* __restrict__ o)
{
  __shared__ float Qs[64][65], Ks[64][65], Vs[64][65], Ps[64][65];
  __shared__ float m_s[64], l_s[64];
  const int t  = threadIdx.x;
  const int qt = blockIdx.x;
  const int bh = blockIdx.y;
  const int b  = bh / HH, hd = bh % HH;
  const float* qbase = qkv + (size_t)b * SS * D3 + hd * DHH;
  const float* kbase = qbase + DD;
  const float* vbase = qbase + 2 * DD;

  #pragma unroll
  for (int jj = 0; jj < 4; ++jj) {
    int idx = t + 256 * jj;
    int r = idx >> 4, c4 = (idx & 15) * 4;
    float4 v = *(const float4*)(qbase + (size_t)(qt * 64 + r) * D3 + c4);
    Qs[r][c4 + 0] = v.x * 0.125f;
    Qs[r][c4 + 1] = v.y * 0.125f;
    Qs[r][c4 + 2] = v.z * 0.125f;
    Qs[r][c4 + 3] = v.w * 0.125f;
  }
  if (t < 64) { m_s[t] = -1e30f; l_s[t] = 0.0f; }
  const int tx = t & 15, ty = t >> 4;
  const int r0 = ty * 4, c0 = tx * 4;
  float oacc[4][4] = {{0.f}};
  __syncthreads();

  for (int kt = 0; kt <= qt; ++kt) {
    #pragma unroll
    for (int jj = 0; jj < 4; ++jj) {
      int idx = t + 256 * jj;
      int r = idx >> 4, c4 = (idx & 15) * 4;
      float4 kv = *(const float4*)(kbase + (size_t)(kt * 64 + r) * D3 + c4);
      float4 vv = *(const float4*)(vbase + (size_t)(kt * 64 + r) * D3 + c4);
      Ks[r][c4 + 0] = kv.x; Ks[r][c4 + 1] = kv.y;
      Ks[r][c4 + 2] = kv.z; Ks[r][c4 + 3] = kv.w;
      Vs[r][c4 + 0] = vv.x; Vs[r][c4 + 1] = vv.y;
      Vs[r][c4 + 2] = vv.z; Vs[r][c4 + 3] = vv.w;
    }
    __syncthreads();

    float sc[4][4] = {{0.f}};
    for (int d = 0; d < 64; ++d) {
      float qa[4], kb[4];
      #pragma unroll
      for (int i = 0; i < 4; ++i) qa[i] = Qs[r0 + i][d];
      #pragma unroll
      for (int j = 0; j < 4; ++j) kb[j] = Ks[c0 + j][d];
      #pragma unroll
      for (int i = 0; i < 4; ++i)
        #pragma unroll
        for (int j = 0; j < 4; ++j)
          sc[i][j] = fmaf(qa[i], kb[j], sc[i][j]);
    }
    if (kt == qt) {
      #pragma unroll
      for (int i = 0; i < 4; ++i)
        #pragma unroll
        for (int j = 0; j < 4; ++j)
          if (c0 + j > r0 + i) sc[i][j] = -1e30f;
    }
    #pragma unroll
    for (int i = 0; i < 4; ++i) {
      float mx = fmaxf(fmaxf(sc[i][0], sc[i][1]), fmaxf(sc[i][2], sc[i][3]));
      #pragma unroll
      for (int off = 1; off < 16; off <<= 1) mx = fmaxf(mx, __shfl_xor(mx, off));
      float mold = m_s[r0 + i];
      float mnew = fmaxf(mold, mx);
      float rsum = 0.f;
      #pragma unroll
      for (int j = 0; j < 4; ++j) {
        float p = __expf(sc[i][j] - mnew);
        Ps[r0 + i][c0 + j] = p;
        rsum += p;
      }
      #pragma unroll
      for (int off = 1; off < 16; off <<= 1) rsum += __shfl_xor(rsum, off);
      float alpha = __expf(mold - mnew);
      #pragma unroll
      for (int j = 0; j < 4; ++j) oacc[i][j] *= alpha;
      if (tx == 0) { m_s[r0 + i] = mnew; l_s[r0 + i] = l_s[r0 + i] * alpha + rsum; }
    }
    __syncthreads();

    for (int c = 0; c < 64; ++c) {
      float pa[4], vb[4];
      #pragma unroll
      for (int i = 0; i < 4; ++i) pa[i] = Ps[r0 + i][c];
      #pragma unroll
      for (int j = 0; j < 4; ++j) vb[j] = Vs[c][c0 + j];
      #pragma unroll
      for (int i = 0; i < 4; ++i)
        #pragma unroll
        for (int j = 0; j < 4; ++j)
          oacc[i][j] = fmaf(pa[i], vb[j], oacc[i][j]);
    }
    __syncthreads();
  }

  #pragma unroll
  for (int i = 0; i < 4; ++i) {
    float linv = 1.0f / l_s[r0 + i];
    ushort4 ov = {f2bf_bits(oacc[i][0] * linv), f2bf_bits(oacc[i][1] * linv),
                  f2bf_bits(oacc[i][2] * linv), f2bf_bits(oacc[i][3] * linv)};
    *(ushort4*)((unsigned short*)o + ((size_t)b * SS + qt * 64 + r0 + i) * DD + hd * DHH + c0) = ov;
  }
}

extern "C" void kernel_launch(void* const* d_in, const int* in_sizes, int n_in,
                              void* d_out, int out_size, void* d_ws, size_t ws_size,
                              hipStream_t stream)
{
  (void)in_sizes; (void)n_in; (void)out_size; (void)ws_size;
  const int*   ids    = (const int*)d_in[0];
  const int*   rfids  = (const int*)d_in[1];
  const float* wte    = (const float*)d_in[2];
  const float* wte_rf = (const float*)d_in[3];
  const float* wpe    = (const float*)d_in[4];
  const float* ln1_g  = (const float*)d_in[5];
  const float* ln1_b  = (const float*)d_in[6];
  const float* attn_w = (const float*)d_in[7];
  const float* attn_b = (const float*)d_in[8];
  const float* proj_w = (const float*)d_in[9];
  const float* proj_b = (const float*)d_in[10];
  const float* ln2_g  = (const float*)d_in[11];
  const float* ln2_b  = (const float*)d_in[12];
  const float* fc_w   = (const float*)d_in[13];
  const float* fc_b   = (const float*)d_in[14];
  const float* fc2_w  = (const float*)d_in[15];
  const float* fc2_b  = (const float*)d_in[16];
  const float* lnf_g  = (const float*)d_in[17];
  const float* lnf_b  = (const float*)d_in[18];

  const int T = BB * SS;  // 4096 tokens
  const size_t TD = (size_t)T * DD;
  // workspace layout (70.8 MB total; a/att share one buffer — disjoint liveness;
  // ff aliases dead qkvb; weight transposes are per-layer into one scratch):
  float* ws   = (float*)d_ws;
  float* h    = ws;                             // [T][D] fp32        12.6 MB
  float* qkvb = h + TD;                         // [T][3D] fp32       37.7 MB
  bf16*  ff   = (bf16*)qkvb;                    // [T][DF] bf16 (alias)
  bf16*  a    = (bf16*)(qkvb + (size_t)T * D3); // [T][D] bf16         6.3 MB
  bf16*  att  = a;                              // alias (disjoint liveness)
  bf16*  awt  = a + TD;                         // [3D][D] bf16        3.5 MB
  bf16*  pwt  = awt + (size_t)D3 * DD;          // [D][D]              1.2 MB
  bf16*  fwt  = pwt + (size_t)DD * DD;          // [DF][D]             4.7 MB
  bf16*  f2wt = fwt + (size_t)DFF * DD;         // [D][DF]             4.7 MB

  embed_kernel<<<dim3((T * DD / 4) / 256), 256, 0, stream>>>(ids, rfids, wte, wte_rf, wpe, h);

  for (int l = 0; l < NLAYER; ++l) {
    // per-layer weight transpose+cast: W[K][N] -> Wt[N][K] bf16
    transpose_cast<<<dim3(D3 / 32,  DD / 32),  256, 0, stream>>>(attn_w + (size_t)l * DD * D3,  awt,  DD,  D3);
    transpose_cast<<<dim3(DD / 32,  DD / 32),  256, 0, stream>>>(proj_w + (size_t)l * DD * DD,  pwt,  DD,  DD);
    transpose_cast<<<dim3(DFF / 32, DD / 32),  256, 0, stream>>>(fc_w   + (size_t)l * DD * DFF, fwt,  DD,  DFF);
    transpose_cast<<<dim3(DD / 32,  DFF / 32), 256, 0, stream>>>(fc2_w  + (size_t)l * DFF * DD, f2wt, DFF, DD);

    ln_kernel<bf16><<<T, 192, 0, stream>>>(h, ln1_g + (size_t)l * DD, ln1_b + (size_t)l * DD, a);
    gemm_bf16<0, float><<<dim3(D3 / 128, T / 128), 256, 0, stream>>>(
        a, awt, attn_b + (size_t)l * D3, nullptr, qkvb, T, D3, DD);
    attn_kernel<<<dim3(SS / 64, BB * HH), 256, 0, stream>>>(qkvb, att);
    gemm_bf16<1, float><<<dim3(DD / 128, T / 128), 256, 0, stream>>>(
        att, pwt, proj_b + (size_t)l * DD, h, h, T, DD, DD);
    ln_kernel<bf16><<<T, 192, 0, stream>>>(h, ln2_g + (size_t)l * DD, ln2_b + (size_t)l * DD, a);
    gemm_bf16<2, bf16><<<dim3(DFF / 128, T / 128), 256, 0, stream>>>(
        a, fwt, fc_b + (size_t)l * DFF, nullptr, ff, T, DFF, DD);
    gemm_bf16<1, float><<<dim3(DD / 128, T / 128), 256, 0, stream>>>(
        ff, f2wt, fc2_b + (size_t)l * DD, h, h, T, DD, DFF);
  }
  ln_kernel<float><<<T, 192, 0, stream>>>(h, lnf_g, lnf_b, (float*)d_out);
}

// Round 4
// 2407.534 us; speedup vs baseline: 2.9527x; 1.5864x over previous
//
#include <hip/hip_runtime.h>
#include <hip/hip_bf16.h>
#include <math.h>

#define BB 4
#define SS 1024
#define DD 768
#define HH 12
#define NLAYER 6
#define DHH 64
#define DFF 3072
#define D3 2304
#define LN_EPS 1e-5f

typedef __hip_bfloat16 bf16;
typedef short bf16x8 __attribute__((ext_vector_type(8)));
typedef float f32x4 __attribute__((ext_vector_type(4)));

__device__ __forceinline__ void gload_lds16(const void* g, void* l) {
  __builtin_amdgcn_global_load_lds(
      (const __attribute__((address_space(1))) void*)g,
      (__attribute__((address_space(3))) void*)l, 16, 0, 0);
}

__device__ __forceinline__ unsigned short f2bf_bits(float x) {
  bf16 h = __float2bfloat16(x);
  union { bf16 h; unsigned short u; } c; c.h = h; return c.u;
}

// ---------------- embedding: h = wte[ids] + wte_rf[rf] + wpe[s] ----------------
__global__ __launch_bounds__(256) void embed_kernel(
    const int* __restrict__ ids, const int* __restrict__ rf,
    const float* __restrict__ wte, const float* __restrict__ wte_rf,
    const float* __restrict__ wpe, float* __restrict__ h)
{
  int idx = blockIdx.x * 256 + threadIdx.x;
  int token = idx / (DD / 4);
  int c4 = (idx % (DD / 4)) * 4;
  int s = token % SS;
  int id  = ids[token];
  int rid = rf[token];
  float4 a = *(const float4*)(wte    + (size_t)id  * DD + c4);
  float4 b = *(const float4*)(wte_rf + (size_t)rid * DD + c4);
  float4 c = *(const float4*)(wpe    + (size_t)s   * DD + c4);
  float4 o;
  o.x = a.x + b.x + c.x;
  o.y = a.y + b.y + c.y;
  o.z = a.z + b.z + c.z;
  o.w = a.w + b.w + c.w;
  *(float4*)(h + (size_t)token * DD + c4) = o;
}

// ---------------- weight transpose+cast: W[K][N] fp32 -> Wt[N][K] bf16 ----------
__global__ __launch_bounds__(256) void transpose_cast(
    const float* __restrict__ W, bf16* __restrict__ Wt, int K, int N)
{
  __shared__ float tile[32][33];
  int n0 = blockIdx.x * 32, k0 = blockIdx.y * 32;
  int tx = threadIdx.x & 31, ty = threadIdx.x >> 5;
  #pragma unroll
  for (int i = 0; i < 4; ++i)
    tile[ty + 8 * i][tx] = W[(size_t)(k0 + ty + 8 * i) * N + n0 + tx];
  __syncthreads();
  #pragma unroll
  for (int i = 0; i < 4; ++i)
    Wt[(size_t)(n0 + ty + 8 * i) * K + k0 + tx] = __float2bfloat16(tile[tx][ty + 8 * i]);
}

// ---------------- V transpose: qkv V-block [s][d] bf16 -> vt[bh][d][s] bf16 ------
__global__ __launch_bounds__(256) void vtrans_kernel(
    const bf16* __restrict__ qkv, bf16* __restrict__ vt)
{
  __shared__ unsigned short tile[32][34];
  int bh = blockIdx.z, b = bh / HH, h = bh % HH;
  int s0 = blockIdx.x * 32, d0 = blockIdx.y * 32;
  int tx = threadIdx.x & 31, ty = threadIdx.x >> 5;
  const unsigned short* src =
      (const unsigned short*)qkv + (size_t)b * SS * D3 + 2 * DD + h * DHH;
  #pragma unroll
  for (int i = 0; i < 4; ++i)
    tile[ty + 8 * i][tx] = src[(size_t)(s0 + ty + 8 * i) * D3 + d0 + tx];
  __syncthreads();
  unsigned short* dst = (unsigned short*)vt + (size_t)bh * DHH * SS;
  #pragma unroll
  for (int i = 0; i < 4; ++i)
    dst[(size_t)(d0 + ty + 8 * i) * SS + s0 + tx] = tile[tx][ty + 8 * i];
}

// ---------------- LayerNorm: one block (192 threads) per row of 768 ----------------
template <typename OutT>
__global__ __launch_bounds__(192) void ln_kernel(
    const float* __restrict__ x, const float* __restrict__ g,
    const float* __restrict__ bb, OutT* __restrict__ y)
{
  __shared__ float red[2][3];
  int row = blockIdx.x;
  int t = threadIdx.x;
  const float* xr = x + (size_t)row * DD;
  float4 v = *(const float4*)(xr + t * 4);
  float s  = v.x + v.y + v.z + v.w;
  float sq = v.x * v.x + v.y * v.y + v.z * v.z + v.w * v.w;
  #pragma unroll
  for (int off = 32; off > 0; off >>= 1) {
    s  += __shfl_down(s, off);
    sq += __shfl_down(sq, off);
  }
  int wave = t >> 6, lane = t & 63;
  if (lane == 0) { red[0][wave] = s; red[1][wave] = sq; }
  __syncthreads();
  s  = red[0][0] + red[0][1] + red[0][2];
  sq = red[1][0] + red[1][1] + red[1][2];
  float mu   = s * (1.0f / DD);
  float var  = sq * (1.0f / DD) - mu * mu;
  float rstd = rsqrtf(var + LN_EPS);
  float4 gv = *(const float4*)(g  + t * 4);
  float4 bv = *(const float4*)(bb + t * 4);
  float o0 = (v.x - mu) * rstd * gv.x + bv.x;
  float o1 = (v.y - mu) * rstd * gv.y + bv.y;
  float o2 = (v.z - mu) * rstd * gv.z + bv.z;
  float o3 = (v.w - mu) * rstd * gv.w + bv.w;
  if constexpr (sizeof(OutT) == 4) {
    float4 o = {o0, o1, o2, o3};
    *(float4*)((float*)y + (size_t)row * DD + t * 4) = o;
  } else {
    ushort4 o = {f2bf_bits(o0), f2bf_bits(o1), f2bf_bits(o2), f2bf_bits(o3)};
    *(ushort4*)((unsigned short*)y + (size_t)row * DD + t * 4) = o;
  }
}

__device__ __forceinline__ float gelu_f(float x) {
  float x3 = x * x * x;
  return 0.5f * x * (1.0f + tanhf(0.7978845608028654f * (x + 0.044715f * x3)));
}

// ---------------- bf16 MFMA GEMM: C[M,N] = A[M,K] @ Wt[N,K]^T + bias -------------
// m97 structure: 128x128 tile, BK=32, 4 waves (2x2), 16 mfma_16x16x32 per K-step.
// MODE 0: +bias   MODE 1: +bias+R(fp32)   MODE 2: gelu(+bias)
template <int MODE, typename OutT>
__global__ __launch_bounds__(256) void gemm_bf16(
    const bf16* __restrict__ A,   // [M][K]
    const bf16* __restrict__ Wt,  // [N][K]
    const float* __restrict__ bias,
    const float* __restrict__ R,
    OutT* __restrict__ C, int M, int N, int K)
{
  __shared__ alignas(16) unsigned short As[4][128][8];
  __shared__ alignas(16) unsigned short Bs[4][128][8];
  const int t = threadIdx.x;
  const int lane = t & 63, wid = t >> 6;
  const int wr = wid >> 1, wc = wid & 1;
  const int bm = blockIdx.y * 128, bn = blockIdx.x * 128;

  f32x4 acc[4][4] = {};

  const int c0 = t, c1 = t + 256;
  const unsigned short* Ag0 = (const unsigned short*)A + (size_t)(bm + (c0 & 127)) * K + (c0 >> 7) * 8;
  const unsigned short* Ag1 = (const unsigned short*)A + (size_t)(bm + (c1 & 127)) * K + (c1 >> 7) * 8;
  const unsigned short* Bg0 = (const unsigned short*)Wt + (size_t)(bn + (c0 & 127)) * K + (c0 >> 7) * 8;
  const unsigned short* Bg1 = (const unsigned short*)Wt + (size_t)(bn + (c1 & 127)) * K + (c1 >> 7) * 8;
  char* AsB = (char*)As;
  char* BsB = (char*)Bs;

  const int abase = (lane >> 4) * 2048 + (wr * 64 + (lane & 15)) * 16;
  const int bbase = (lane >> 4) * 2048 + (wc * 64 + (lane & 15)) * 16;

  for (int k0 = 0; k0 < K; k0 += 32) {
    gload_lds16(Ag0 + k0, AsB + c0 * 16);
    gload_lds16(Ag1 + k0, AsB + c1 * 16);
    gload_lds16(Bg0 + k0, BsB + c0 * 16);
    gload_lds16(Bg1 + k0, BsB + c1 * 16);
    __syncthreads();

    bf16x8 a[4], b[4];
    #pragma unroll
    for (int m = 0; m < 4; ++m) a[m] = *(const bf16x8*)(AsB + abase + m * 256);
    #pragma unroll
    for (int n = 0; n < 4; ++n) b[n] = *(const bf16x8*)(BsB + bbase + n * 256);
    #pragma unroll
    for (int m = 0; m < 4; ++m)
      #pragma unroll
      for (int n = 0; n < 4; ++n)
        acc[m][n] = __builtin_amdgcn_mfma_f32_16x16x32_bf16(a[m], b[n], acc[m][n], 0, 0, 0);
    __syncthreads();
  }

  const int colg = lane & 15, rowg = (lane >> 4) * 4;
  #pragma unroll
  for (int m = 0; m < 4; ++m) {
    #pragma unroll
    for (int n = 0; n < 4; ++n) {
      int col = bn + wc * 64 + n * 16 + colg;
      float bv = bias[col];
      #pragma unroll
      for (int r = 0; r < 4; ++r) {
        int row = bm + wr * 64 + m * 16 + rowg + r;
        float v = acc[m][n][r] + bv;
        if constexpr (MODE == 1) v += R[(size_t)row * N + col];
        if constexpr (MODE == 2) v = gelu_f(v);
        if constexpr (sizeof(OutT) == 4) ((float*)C)[(size_t)row * N + col] = v;
        else ((bf16*)C)[(size_t)row * N + col] = __float2bfloat16(v);
      }
    }
  }
}

// ---------------- MFMA flash attention (bf16 in, fp32 softmax, causal) ----------
// One wave = 16 q-rows. S^T = mfma(K,Q) so softmax state lives at q=lane&15;
// O^T = mfma(V^T, P) accumulates with cols q=lane&15 (no cross-lane rescale).
// K and V^T fragments read directly from global (L1/L2-resident); no barriers.
__global__ __launch_bounds__(256) void attn_mfma(
    const bf16* __restrict__ qkv,  // [B*S][3D] bf16
    const bf16* __restrict__ vt,   // [B*H][64][S] bf16
    bf16* __restrict__ o)          // [B*S][D] bf16
{
  __shared__ unsigned short plds[4][16][40];  // per-wave P rows, pitch 80B (16B-aligned frags)
  const int bid = blockIdx.x;                 // 768 = 48 bh * 16 qtiles
  const int swz = (bid & 7) * 96 + (bid >> 3);  // XCD-contiguous in bh-major order
  const int bh = swz >> 4, qt = swz & 15;
  const int b = bh / HH, h = bh % HH;
  const int w = threadIdx.x >> 6, lane = threadIdx.x & 63;
  const int g = lane >> 4, l15 = lane & 15;
  const int q0 = qt * 64 + w * 16;
  const int qg = q0 + l15;

  const bf16* qbase = qkv + (size_t)b * SS * D3 + h * DHH;
  const bf16* kbase = qbase + DD;
  const bf16* vbase = vt + (size_t)bh * DHH * SS;

  // Q fragments (B-operand): col=l15 -> q row; k=d = d0 + g*8 + j
  bf16x8 qf0 = *(const bf16x8*)(qbase + (size_t)(q0 + l15) * D3 + g * 8);
  bf16x8 qf1 = *(const bf16x8*)(qbase + (size_t)(q0 + l15) * D3 + 32 + g * 8);

  f32x4 oacc[4] = {};            // O^T blocks: row d = blk*16 + 4g + r, col q = l15
  float m = -1e30f, l = 0.f;     // softmax state for q = qg
  const int kvend = q0 + 16;

  for (int kv0 = 0; kv0 < kvend; kv0 += 32) {
    // S^T tiles (rows kv, cols q): A=K-frag, B=Q-frag
    f32x4 st[2];
    #pragma unroll
    for (int tt = 0; tt < 2; ++tt) {
      const bf16* kr = kbase + (size_t)(kv0 + tt * 16 + l15) * D3 + g * 8;
      bf16x8 kf0 = *(const bf16x8*)kr;
      bf16x8 kf1 = *(const bf16x8*)(kr + 32);
      f32x4 z = {0.f, 0.f, 0.f, 0.f};
      z = __builtin_amdgcn_mfma_f32_16x16x32_bf16(kf0, qf0, z, 0, 0, 0);
      z = __builtin_amdgcn_mfma_f32_16x16x32_bf16(kf1, qf1, z, 0, 0, 0);
      st[tt] = z;
    }
    // scale + causal mask (kv > q -> -inf); lane's kv = kv0 + tt*16 + 4g + r
    float sv[8];
    #pragma unroll
    for (int tt = 0; tt < 2; ++tt)
      #pragma unroll
      for (int r = 0; r < 4; ++r) {
        int kv = kv0 + tt * 16 + 4 * g + r;
        float x = st[tt][r] * 0.125f;
        sv[tt * 4 + r] = (kv > qg) ? -1e30f : x;
      }
    // online softmax (reduce over kv: regs + lanes ^16 ^32)
    float pmax = sv[0];
    #pragma unroll
    for (int i = 1; i < 8; ++i) pmax = fmaxf(pmax, sv[i]);
    pmax = fmaxf(pmax, __shfl_xor(pmax, 16));
    pmax = fmaxf(pmax, __shfl_xor(pmax, 32));
    float mnew = fmaxf(m, pmax);
    float alpha = __expf(m - mnew);
    float rsum = 0.f;
    ushort4 pA, pB;
    {
      float p0 = __expf(sv[0] - mnew), p1 = __expf(sv[1] - mnew);
      float p2 = __expf(sv[2] - mnew), p3 = __expf(sv[3] - mnew);
      float p4 = __expf(sv[4] - mnew), p5 = __expf(sv[5] - mnew);
      float p6 = __expf(sv[6] - mnew), p7 = __expf(sv[7] - mnew);
      rsum = ((p0 + p1) + (p2 + p3)) + ((p4 + p5) + (p6 + p7));
      pA.x = f2bf_bits(p0); pA.y = f2bf_bits(p1); pA.z = f2bf_bits(p2); pA.w = f2bf_bits(p3);
      pB.x = f2bf_bits(p4); pB.y = f2bf_bits(p5); pB.z = f2bf_bits(p6); pB.w = f2bf_bits(p7);
    }
    rsum += __shfl_xor(rsum, 16);
    rsum += __shfl_xor(rsum, 32);
    l = l * alpha + rsum; m = mnew;
    #pragma unroll
    for (int blk = 0; blk < 4; ++blk)
      #pragma unroll
      for (int r = 0; r < 4; ++r) oacc[blk][r] *= alpha;

    // P -> LDS row q=l15: lane writes kv-local {4g..4g+3} and {16+4g..+3}
    *(ushort4*)&plds[w][l15][4 * g]      = pA;
    *(ushort4*)&plds[w][l15][16 + 4 * g] = pB;
    asm volatile("s_waitcnt lgkmcnt(0)" ::: "memory");  // cross-lane P visible
    __builtin_amdgcn_sched_barrier(0);

    // P-frag (B): col=l15=q, k=kv-local g*8+j
    bf16x8 pf = *(const bf16x8*)&plds[w][l15][g * 8];
    // O^T += mfma(V^T-frag, P-frag) per d-block
    #pragma unroll
    for (int blk = 0; blk < 4; ++blk) {
      bf16x8 vf = *(const bf16x8*)(vbase + (size_t)(blk * 16 + l15) * SS + kv0 + g * 8);
      oacc[blk] = __builtin_amdgcn_mfma_f32_16x16x32_bf16(vf, pf, oacc[blk], 0, 0, 0);
    }
  }

  float linv = 1.0f / l;
  unsigned short* ob = (unsigned short*)o + (size_t)(b * SS + qg) * DD + h * DHH;
  #pragma unroll
  for (int blk = 0; blk < 4; ++blk) {
    ushort4 ov = {f2bf_bits(oacc[blk][0] * linv), f2bf_bits(oacc[blk][1] * linv),
                  f2bf_bits(oacc[blk][2] * linv), f2bf_bits(oacc[blk][3] * linv)};
    *(ushort4*)(ob + blk * 16 + 4 * g) = ov;
  }
}

extern "C" void kernel_launch(void* const* d_in, const int* in_sizes, int n_in,
                              void* d_out, int out_size, void* d_ws, size_t ws_size,
                              hipStream_t stream)
{
  (void)in_sizes; (void)n_in; (void)out_size; (void)ws_size;
  const int*   ids    = (const int*)d_in[0];
  const int*   rfids  = (const int*)d_in[1];
  const float* wte    = (const float*)d_in[2];
  const float* wte_rf = (const float*)d_in[3];
  const float* wpe    = (const float*)d_in[4];
  const float* ln1_g  = (const float*)d_in[5];
  const float* ln1_b  = (const float*)d_in[6];
  const float* attn_w = (const float*)d_in[7];
  const float* attn_b = (const float*)d_in[8];
  const float* proj_w = (const float*)d_in[9];
  const float* proj_b = (const float*)d_in[10];
  const float* ln2_g  = (const float*)d_in[11];
  const float* ln2_b  = (const float*)d_in[12];
  const float* fc_w   = (const float*)d_in[13];
  const float* fc_b   = (const float*)d_in[14];
  const float* fc2_w  = (const float*)d_in[15];
  const float* fc2_b  = (const float*)d_in[16];
  const float* lnf_g  = (const float*)d_in[17];
  const float* lnf_b  = (const float*)d_in[18];

  const int T = BB * SS;  // 4096 tokens
  const size_t TD = (size_t)T * DD;
  // workspace (58.2 MB): ff aliases [qkvb|vt] exactly (3D + D = DF);
  // a/att share one buffer (disjoint liveness); weights transposed per-layer.
  float* h    = (float*)d_ws;                   // [T][D] fp32        12.6 MB
  bf16*  qkvb = (bf16*)(h + TD);                // [T][3D] bf16       18.9 MB
  bf16*  vtb  = qkvb + (size_t)T * D3;          // [BH][64][S] bf16    6.3 MB
  bf16*  ff   = qkvb;                           // [T][DF] bf16 (alias)
  bf16*  a    = vtb + TD;                       // [T][D] bf16         6.3 MB
  bf16*  att  = a;                              // alias
  bf16*  awt  = a + TD;                         // [3D][D]             3.5 MB
  bf16*  pwt  = awt + (size_t)D3 * DD;          // [D][D]              1.2 MB
  bf16*  fwt  = pwt + (size_t)DD * DD;          // [DF][D]             4.7 MB
  bf16*  f2wt = fwt + (size_t)DFF * DD;         // [D][DF]             4.7 MB

  embed_kernel<<<dim3((T * DD / 4) / 256), 256, 0, stream>>>(ids, rfids, wte, wte_rf, wpe, h);

  for (int l = 0; l < NLAYER; ++l) {
    transpose_cast<<<dim3(D3 / 32,  DD / 32),  256, 0, stream>>>(attn_w + (size_t)l * DD * D3,  awt,  DD,  D3);
    transpose_cast<<<dim3(DD / 32,  DD / 32),  256, 0, stream>>>(proj_w + (size_t)l * DD * DD,  pwt,  DD,  DD);
    transpose_cast<<<dim3(DFF / 32, DD / 32),  256, 0, stream>>>(fc_w   + (size_t)l * DD * DFF, fwt,  DD,  DFF);
    transpose_cast<<<dim3(DD / 32,  DFF / 32), 256, 0, stream>>>(fc2_w  + (size_t)l * DFF * DD, f2wt, DFF, DD);

    ln_kernel<bf16><<<T, 192, 0, stream>>>(h, ln1_g + (size_t)l * DD, ln1_b + (size_t)l * DD, a);
    gemm_bf16<0, bf16><<<dim3(D3 / 128, T / 128), 256, 0, stream>>>(
        a, awt, attn_b + (size_t)l * D3, nullptr, qkvb, T, D3, DD);
    vtrans_kernel<<<dim3(SS / 32, DHH / 32, BB * HH), 256, 0, stream>>>(qkvb, vtb);
    attn_mfma<<<BB * HH * (SS / 64), 256, 0, stream>>>(qkvb, vtb, att);
    gemm_bf16<1, float><<<dim3(DD / 128, T / 128), 256, 0, stream>>>(
        att, pwt, proj_b + (size_t)l * DD, h, h, T, DD, DD);
    ln_kernel<bf16><<<T, 192, 0, stream>>>(h, ln2_g + (size_t)l * DD, ln2_b + (size_t)l * DD, a);
    gemm_bf16<2, bf16><<<dim3(DFF / 128, T / 128), 256, 0, stream>>>(
        a, fwt, fc_b + (size_t)l * DFF, nullptr, ff, T, DFF, DD);
    gemm_bf16<1, float><<<dim3(DD / 128, T / 128), 256, 0, stream>>>(
        ff, f2wt, fc2_b + (size_t)l * DD, h, h, T, DD, DFF);
  }
  ln_kernel<float><<<T, 192, 0, stream>>>(h, lnf_g, lnf_b, (float*)d_out);
}

// Round 5
// 2190.649 us; speedup vs baseline: 3.2450x; 1.0990x over previous
//
#include <hip/hip_runtime.h>
#include <hip/hip_bf16.h>
#include <math.h>

#define BB 4
#define SS 1024
#define DD 768
#define HH 12
#define NLAYER 6
#define DHH 64
#define DFF 3072
#define D3 2304
#define LN_EPS 1e-5f

typedef __hip_bfloat16 bf16;
typedef short bf16x8 __attribute__((ext_vector_type(8)));
typedef float f32x4 __attribute__((ext_vector_type(4)));

__device__ __forceinline__ void gload_lds16(const void* g, void* l) {
  __builtin_amdgcn_global_load_lds(
      (const __attribute__((address_space(1))) void*)g,
      (__attribute__((address_space(3))) void*)l, 16, 0, 0);
}

__device__ __forceinline__ unsigned short f2bf_bits(float x) {
  bf16 h = __float2bfloat16(x);
  union { bf16 h; unsigned short u; } c; c.h = h; return c.u;
}

// ---------------- embedding: h = wte[ids] + wte_rf[rf] + wpe[s] ----------------
__global__ __launch_bounds__(256) void embed_kernel(
    const int* __restrict__ ids, const int* __restrict__ rf,
    const float* __restrict__ wte, const float* __restrict__ wte_rf,
    const float* __restrict__ wpe, float* __restrict__ h)
{
  int idx = blockIdx.x * 256 + threadIdx.x;
  int token = idx / (DD / 4);
  int c4 = (idx % (DD / 4)) * 4;
  int s = token % SS;
  int id  = ids[token];
  int rid = rf[token];
  float4 a = *(const float4*)(wte    + (size_t)id  * DD + c4);
  float4 b = *(const float4*)(wte_rf + (size_t)rid * DD + c4);
  float4 c = *(const float4*)(wpe    + (size_t)s   * DD + c4);
  float4 o;
  o.x = a.x + b.x + c.x;
  o.y = a.y + b.y + c.y;
  o.z = a.z + b.z + c.z;
  o.w = a.w + b.w + c.w;
  *(float4*)(h + (size_t)token * DD + c4) = o;
}

// ---------------- weight transpose+cast: W[K][N] fp32 -> Wt[N][K] bf16 ----------
__global__ __launch_bounds__(256) void transpose_cast(
    const float* __restrict__ W, bf16* __restrict__ Wt, int K, int N)
{
  __shared__ float tile[32][33];
  int n0 = blockIdx.x * 32, k0 = blockIdx.y * 32;
  int tx = threadIdx.x & 31, ty = threadIdx.x >> 5;
  #pragma unroll
  for (int i = 0; i < 4; ++i)
    tile[ty + 8 * i][tx] = W[(size_t)(k0 + ty + 8 * i) * N + n0 + tx];
  __syncthreads();
  #pragma unroll
  for (int i = 0; i < 4; ++i)
    Wt[(size_t)(n0 + ty + 8 * i) * K + k0 + tx] = __float2bfloat16(tile[tx][ty + 8 * i]);
}

// ---------------- V transpose: qkv V-block [s][d] bf16 -> vt[bh][d][s] bf16 ------
__global__ __launch_bounds__(256) void vtrans_kernel(
    const bf16* __restrict__ qkv, bf16* __restrict__ vt)
{
  __shared__ unsigned short tile[32][34];
  int bh = blockIdx.z, b = bh / HH, h = bh % HH;
  int s0 = blockIdx.x * 32, d0 = blockIdx.y * 32;
  int tx = threadIdx.x & 31, ty = threadIdx.x >> 5;
  const unsigned short* src =
      (const unsigned short*)qkv + (size_t)b * SS * D3 + 2 * DD + h * DHH;
  #pragma unroll
  for (int i = 0; i < 4; ++i)
    tile[ty + 8 * i][tx] = src[(size_t)(s0 + ty + 8 * i) * D3 + d0 + tx];
  __syncthreads();
  unsigned short* dst = (unsigned short*)vt + (size_t)bh * DHH * SS;
  #pragma unroll
  for (int i = 0; i < 4; ++i)
    dst[(size_t)(d0 + ty + 8 * i) * SS + s0 + tx] = tile[tx][ty + 8 * i];
}

// ---------------- LayerNorm: one block (192 threads) per row of 768 ----------------
template <typename OutT>
__global__ __launch_bounds__(192) void ln_kernel(
    const float* __restrict__ x, const float* __restrict__ g,
    const float* __restrict__ bb, OutT* __restrict__ y)
{
  __shared__ float red[2][3];
  int row = blockIdx.x;
  int t = threadIdx.x;
  const float* xr = x + (size_t)row * DD;
  float4 v = *(const float4*)(xr + t * 4);
  float s  = v.x + v.y + v.z + v.w;
  float sq = v.x * v.x + v.y * v.y + v.z * v.z + v.w * v.w;
  #pragma unroll
  for (int off = 32; off > 0; off >>= 1) {
    s  += __shfl_down(s, off);
    sq += __shfl_down(sq, off);
  }
  int wave = t >> 6, lane = t & 63;
  if (lane == 0) { red[0][wave] = s; red[1][wave] = sq; }
  __syncthreads();
  s  = red[0][0] + red[0][1] + red[0][2];
  sq = red[1][0] + red[1][1] + red[1][2];
  float mu   = s * (1.0f / DD);
  float var  = sq * (1.0f / DD) - mu * mu;
  float rstd = rsqrtf(var + LN_EPS);
  float4 gv = *(const float4*)(g  + t * 4);
  float4 bv = *(const float4*)(bb + t * 4);
  float o0 = (v.x - mu) * rstd * gv.x + bv.x;
  float o1 = (v.y - mu) * rstd * gv.y + bv.y;
  float o2 = (v.z - mu) * rstd * gv.z + bv.z;
  float o3 = (v.w - mu) * rstd * gv.w + bv.w;
  if constexpr (sizeof(OutT) == 4) {
    float4 o = {o0, o1, o2, o3};
    *(float4*)((float*)y + (size_t)row * DD + t * 4) = o;
  } else {
    ushort4 o = {f2bf_bits(o0), f2bf_bits(o1), f2bf_bits(o2), f2bf_bits(o3)};
    *(ushort4*)((unsigned short*)y + (size_t)row * DD + t * 4) = o;
  }
}

__device__ __forceinline__ float gelu_f(float x) {
  float x3 = x * x * x;
  return 0.5f * x * (1.0f + tanhf(0.7978845608028654f * (x + 0.044715f * x3)));
}

// ---------------- bf16 MFMA GEMM, templated tile, double-buffered ----------------
// C[M,N] = A[M,K] @ Wt[N,K]^T + bias.  4 waves arranged (BM/WM)x(BN/WN).
// LDS per buffer interleaved [k8][row][8]; 2-phase prefetch (T3 minimum):
// issue STAGE(next) before ds_read+MFMA(cur), one barrier per K-step.
// XCD swizzle: each XCD owns a contiguous M-stripe (grids are %8==0).
// MODE 0: +bias   MODE 1: +bias+R(fp32)   MODE 2: gelu(+bias)
template <int BM, int BN, int WM, int WN, int MODE, typename OutT>
__global__ __launch_bounds__(256) void gemm_bf16(
    const bf16* __restrict__ A,   // [M][K]
    const bf16* __restrict__ Wt,  // [N][K]
    const float* __restrict__ bias,
    const float* __restrict__ R,
    OutT* __restrict__ C, int M, int N, int K)
{
  constexpr int MR = WM / 16, NR = WN / 16;
  constexpr int WC = BN / WN;
  constexpr int ACH = BM * 4 / 256, BCH = BN * 4 / 256;
  constexpr int ABUF = BM * 64, BBUF = BN * 64;  // bytes per LDS buffer
  static_assert((BM / WM) * (BN / WN) == 4, "4 waves");
  __shared__ alignas(16) char AsB[2 * ABUF];
  __shared__ alignas(16) char BsB[2 * BBUF];
  const int t = threadIdx.x;
  const int lane = t & 63, wid = t >> 6;
  const int wr = wid / WC, wc = wid % WC;
  const int g = lane >> 4, l15 = lane & 15;

  // XCD swizzle: contiguous swz-range per XCD -> contiguous M-stripe
  const int nx = gridDim.x;
  const int nwg = nx * gridDim.y;
  const int bid0 = blockIdx.y * nx + blockIdx.x;
  const int bid = (bid0 & 7) * (nwg >> 3) + (bid0 >> 3);
  const int bm = (bid / nx) * BM, bn = (bid % nx) * BN;

  f32x4 acc[MR][NR] = {};

  const unsigned short* Ag[ACH];
  const unsigned short* Bg[BCH];
  #pragma unroll
  for (int i = 0; i < ACH; ++i) {
    int c = t + i * 256;
    Ag[i] = (const unsigned short*)A + (size_t)(bm + c % BM) * K + (c / BM) * 8;
  }
  #pragma unroll
  for (int i = 0; i < BCH; ++i) {
    int c = t + i * 256;
    Bg[i] = (const unsigned short*)Wt + (size_t)(bn + c % BN) * K + (c / BN) * 8;
  }

  auto stage = [&](int buf, int k0) {
    #pragma unroll
    for (int i = 0; i < ACH; ++i)
      gload_lds16(Ag[i] + k0, AsB + buf * ABUF + (t + i * 256) * 16);
    #pragma unroll
    for (int i = 0; i < BCH; ++i)
      gload_lds16(Bg[i] + k0, BsB + buf * BBUF + (t + i * 256) * 16);
  };

  const int abase = g * (BM * 16) + (wr * WM + l15) * 16;
  const int bbase = g * (BN * 16) + (wc * WN + l15) * 16;

  const int nt = K / 32;
  stage(0, 0);
  __syncthreads();
  for (int tk = 0; tk < nt; ++tk) {
    const int cur = tk & 1;
    if (tk + 1 < nt) stage(cur ^ 1, (tk + 1) * 32);
    bf16x8 a[MR], b[NR];
    #pragma unroll
    for (int m = 0; m < MR; ++m)
      a[m] = *(const bf16x8*)(AsB + cur * ABUF + abase + m * 256);
    #pragma unroll
    for (int n = 0; n < NR; ++n)
      b[n] = *(const bf16x8*)(BsB + cur * BBUF + bbase + n * 256);
    #pragma unroll
    for (int m = 0; m < MR; ++m)
      #pragma unroll
      for (int n = 0; n < NR; ++n)
        acc[m][n] = __builtin_amdgcn_mfma_f32_16x16x32_bf16(a[m], b[n], acc[m][n], 0, 0, 0);
    __syncthreads();
  }

  // epilogue: C/D layout col=lane&15, row=(lane>>4)*4+reg  [m89-verified]
  const int colg = l15, rowg = g * 4;
  #pragma unroll
  for (int m = 0; m < MR; ++m) {
    #pragma unroll
    for (int n = 0; n < NR; ++n) {
      int col = bn + wc * WN + n * 16 + colg;
      float bv = bias[col];
      #pragma unroll
      for (int r = 0; r < 4; ++r) {
        int row = bm + wr * WM + m * 16 + rowg + r;
        float v = acc[m][n][r] + bv;
        if constexpr (MODE == 1) v += R[(size_t)row * N + col];
        if constexpr (MODE == 2) v = gelu_f(v);
        if constexpr (sizeof(OutT) == 4) ((float*)C)[(size_t)row * N + col] = v;
        else ((bf16*)C)[(size_t)row * N + col] = __float2bfloat16(v);
      }
    }
  }
}

// ---------------- MFMA flash attention (bf16 in, fp32 softmax, causal) ----------
__global__ __launch_bounds__(256) void attn_mfma(
    const bf16* __restrict__ qkv,  // [B*S][3D] bf16
    const bf16* __restrict__ vt,   // [B*H][64][S] bf16
    bf16* __restrict__ o)          // [B*S][D] bf16
{
  __shared__ unsigned short plds[4][16][40];
  const int bid = blockIdx.x;                   // 768 = 48 bh * 16 qtiles
  const int swz = (bid & 7) * 96 + (bid >> 3);  // XCD-contiguous, bh-major
  const int bh = swz >> 4, qt = swz & 15;
  const int b = bh / HH, h = bh % HH;
  const int w = threadIdx.x >> 6, lane = threadIdx.x & 63;
  const int g = lane >> 4, l15 = lane & 15;
  const int q0 = qt * 64 + w * 16;
  const int qg = q0 + l15;

  const bf16* qbase = qkv + (size_t)b * SS * D3 + h * DHH;
  const bf16* kbase = qbase + DD;
  const bf16* vbase = vt + (size_t)bh * DHH * SS;

  bf16x8 qf0 = *(const bf16x8*)(qbase + (size_t)(q0 + l15) * D3 + g * 8);
  bf16x8 qf1 = *(const bf16x8*)(qbase + (size_t)(q0 + l15) * D3 + 32 + g * 8);

  f32x4 oacc[4] = {};
  float m = -1e30f, l = 0.f;
  const int kvend = q0 + 16;

  for (int kv0 = 0; kv0 < kvend; kv0 += 32) {
    f32x4 st[2];
    #pragma unroll
    for (int tt = 0; tt < 2; ++tt) {
      const bf16* kr = kbase + (size_t)(kv0 + tt * 16 + l15) * D3 + g * 8;
      bf16x8 kf0 = *(const bf16x8*)kr;
      bf16x8 kf1 = *(const bf16x8*)(kr + 32);
      f32x4 z = {0.f, 0.f, 0.f, 0.f};
      z = __builtin_amdgcn_mfma_f32_16x16x32_bf16(kf0, qf0, z, 0, 0, 0);
      z = __builtin_amdgcn_mfma_f32_16x16x32_bf16(kf1, qf1, z, 0, 0, 0);
      st[tt] = z;
    }
    float sv[8];
    #pragma unroll
    for (int tt = 0; tt < 2; ++tt)
      #pragma unroll
      for (int r = 0; r < 4; ++r) {
        int kv = kv0 + tt * 16 + 4 * g + r;
        float x = st[tt][r] * 0.125f;
        sv[tt * 4 + r] = (kv > qg) ? -1e30f : x;
      }
    float pmax = sv[0];
    #pragma unroll
    for (int i = 1; i < 8; ++i) pmax = fmaxf(pmax, sv[i]);
    pmax = fmaxf(pmax, __shfl_xor(pmax, 16));
    pmax = fmaxf(pmax, __shfl_xor(pmax, 32));
    float mnew = fmaxf(m, pmax);
    float alpha = __expf(m - mnew);
    float rsum = 0.f;
    ushort4 pA, pB;
    {
      float p0 = __expf(sv[0] - mnew), p1 = __expf(sv[1] - mnew);
      float p2 = __expf(sv[2] - mnew), p3 = __expf(sv[3] - mnew);
      float p4 = __expf(sv[4] - mnew), p5 = __expf(sv[5] - mnew);
      float p6 = __expf(sv[6] - mnew), p7 = __expf(sv[7] - mnew);
      rsum = ((p0 + p1) + (p2 + p3)) + ((p4 + p5) + (p6 + p7));
      pA.x = f2bf_bits(p0); pA.y = f2bf_bits(p1); pA.z = f2bf_bits(p2); pA.w = f2bf_bits(p3);
      pB.x = f2bf_bits(p4); pB.y = f2bf_bits(p5); pB.z = f2bf_bits(p6); pB.w = f2bf_bits(p7);
    }
    rsum += __shfl_xor(rsum, 16);
    rsum += __shfl_xor(rsum, 32);
    l = l * alpha + rsum; m = mnew;
    #pragma unroll
    for (int blk = 0; blk < 4; ++blk)
      #pragma unroll
      for (int r = 0; r < 4; ++r) oacc[blk][r] *= alpha;

    *(ushort4*)&plds[w][l15][4 * g]      = pA;
    *(ushort4*)&plds[w][l15][16 + 4 * g] = pB;
    asm volatile("s_waitcnt lgkmcnt(0)" ::: "memory");
    __builtin_amdgcn_sched_barrier(0);

    bf16x8 pf = *(const bf16x8*)&plds[w][l15][g * 8];
    #pragma unroll
    for (int blk = 0; blk < 4; ++blk) {
      bf16x8 vf = *(const bf16x8*)(vbase + (size_t)(blk * 16 + l15) * SS + kv0 + g * 8);
      oacc[blk] = __builtin_amdgcn_mfma_f32_16x16x32_bf16(vf, pf, oacc[blk], 0, 0, 0);
    }
  }

  float linv = 1.0f / l;
  unsigned short* ob = (unsigned short*)o + (size_t)(b * SS + qg) * DD + h * DHH;
  #pragma unroll
  for (int blk = 0; blk < 4; ++blk) {
    ushort4 ov = {f2bf_bits(oacc[blk][0] * linv), f2bf_bits(oacc[blk][1] * linv),
                  f2bf_bits(oacc[blk][2] * linv), f2bf_bits(oacc[blk][3] * linv)};
    *(ushort4*)(ob + blk * 16 + 4 * g) = ov;
  }
}

extern "C" void kernel_launch(void* const* d_in, const int* in_sizes, int n_in,
                              void* d_out, int out_size, void* d_ws, size_t ws_size,
                              hipStream_t stream)
{
  (void)in_sizes; (void)n_in; (void)out_size; (void)ws_size;
  const int*   ids    = (const int*)d_in[0];
  const int*   rfids  = (const int*)d_in[1];
  const float* wte    = (const float*)d_in[2];
  const float* wte_rf = (const float*)d_in[3];
  const float* wpe    = (const float*)d_in[4];
  const float* ln1_g  = (const float*)d_in[5];
  const float* ln1_b  = (const float*)d_in[6];
  const float* attn_w = (const float*)d_in[7];
  const float* attn_b = (const float*)d_in[8];
  const float* proj_w = (const float*)d_in[9];
  const float* proj_b = (const float*)d_in[10];
  const float* ln2_g  = (const float*)d_in[11];
  const float* ln2_b  = (const float*)d_in[12];
  const float* fc_w   = (const float*)d_in[13];
  const float* fc_b   = (const float*)d_in[14];
  const float* fc2_w  = (const float*)d_in[15];
  const float* fc2_b  = (const float*)d_in[16];
  const float* lnf_g  = (const float*)d_in[17];
  const float* lnf_b  = (const float*)d_in[18];

  const int T = BB * SS;  // 4096 tokens
  const size_t TD = (size_t)T * DD;
  // workspace (58.2 MB): ff aliases [qkvb|vt] (3D + D = DF); a/att share.
  float* h    = (float*)d_ws;                   // [T][D] fp32        12.6 MB
  bf16*  qkvb = (bf16*)(h + TD);                // [T][3D] bf16       18.9 MB
  bf16*  vtb  = qkvb + (size_t)T * D3;          // [BH][64][S] bf16    6.3 MB
  bf16*  ff   = qkvb;                           // [T][DF] bf16 (alias)
  bf16*  a    = vtb + TD;                       // [T][D] bf16         6.3 MB
  bf16*  att  = a;                              // alias
  bf16*  awt  = a + TD;                         // [3D][D]             3.5 MB
  bf16*  pwt  = awt + (size_t)D3 * DD;          // [D][D]              1.2 MB
  bf16*  fwt  = pwt + (size_t)DD * DD;          // [DF][D]             4.7 MB
  bf16*  f2wt = fwt + (size_t)DFF * DD;         // [D][DF]             4.7 MB

  embed_kernel<<<dim3((T * DD / 4) / 256), 256, 0, stream>>>(ids, rfids, wte, wte_rf, wpe, h);

  for (int l = 0; l < NLAYER; ++l) {
    transpose_cast<<<dim3(D3 / 32,  DD / 32),  256, 0, stream>>>(attn_w + (size_t)l * DD * D3,  awt,  DD,  D3);
    transpose_cast<<<dim3(DD / 32,  DD / 32),  256, 0, stream>>>(proj_w + (size_t)l * DD * DD,  pwt,  DD,  DD);
    transpose_cast<<<dim3(DFF / 32, DD / 32),  256, 0, stream>>>(fc_w   + (size_t)l * DD * DFF, fwt,  DD,  DFF);
    transpose_cast<<<dim3(DD / 32,  DFF / 32), 256, 0, stream>>>(fc2_w  + (size_t)l * DFF * DD, f2wt, DFF, DD);

    ln_kernel<bf16><<<T, 192, 0, stream>>>(h, ln1_g + (size_t)l * DD, ln1_b + (size_t)l * DD, a);
    gemm_bf16<128, 128, 64, 64, 0, bf16><<<dim3(D3 / 128, T / 128), 256, 0, stream>>>(
        a, awt, attn_b + (size_t)l * D3, nullptr, qkvb, T, D3, DD);
    vtrans_kernel<<<dim3(SS / 32, DHH / 32, BB * HH), 256, 0, stream>>>(qkvb, vtb);
    attn_mfma<<<BB * HH * (SS / 64), 256, 0, stream>>>(qkvb, vtb, att);
    gemm_bf16<64, 128, 32, 64, 1, float><<<dim3(DD / 128, T / 64), 256, 0, stream>>>(
        att, pwt, proj_b + (size_t)l * DD, h, h, T, DD, DD);
    ln_kernel<bf16><<<T, 192, 0, stream>>>(h, ln2_g + (size_t)l * DD, ln2_b + (size_t)l * DD, a);
    gemm_bf16<128, 128, 64, 64, 2, bf16><<<dim3(DFF / 128, T / 128), 256, 0, stream>>>(
        a, fwt, fc_b + (size_t)l * DFF, nullptr, ff, T, DFF, DD);
    gemm_bf16<64, 128, 32, 64, 1, float><<<dim3(DD / 128, T / 64), 256, 0, stream>>>(
        ff, f2wt, fc2_b + (size_t)l * DD, h, h, T, DD, DFF);
  }
  ln_kernel<float><<<T, 192, 0, stream>>>(h, lnf_g, lnf_b, (float*)d_out);
}

// Round 6
// 2057.793 us; speedup vs baseline: 3.4546x; 1.0646x over previous
//
#include <hip/hip_runtime.h>
#include <hip/hip_bf16.h>
#include <math.h>

#define BB 4
#define SS 1024
#define DD 768
#define HH 12
#define NLAYER 6
#define DHH 64
#define DFF 3072
#define D3 2304
#define LN_EPS 1e-5f

typedef __hip_bfloat16 bf16;
typedef short bf16x8 __attribute__((ext_vector_type(8)));
typedef float f32x4 __attribute__((ext_vector_type(4)));

__device__ __forceinline__ void gload_lds16(const void* g, void* l) {
  __builtin_amdgcn_global_load_lds(
      (const __attribute__((address_space(1))) void*)g,
      (__attribute__((address_space(3))) void*)l, 16, 0, 0);
}

__device__ __forceinline__ unsigned short f2bf_bits(float x) {
  bf16 h = __float2bfloat16(x);
  union { bf16 h; unsigned short u; } c; c.h = h; return c.u;
}

// ---------------- embedding: h = wte[ids] + wte_rf[rf] + wpe[s] ----------------
__global__ __launch_bounds__(256) void embed_kernel(
    const int* __restrict__ ids, const int* __restrict__ rf,
    const float* __restrict__ wte, const float* __restrict__ wte_rf,
    const float* __restrict__ wpe, float* __restrict__ h)
{
  int idx = blockIdx.x * 256 + threadIdx.x;
  int token = idx / (DD / 4);
  int c4 = (idx % (DD / 4)) * 4;
  int s = token % SS;
  int id  = ids[token];
  int rid = rf[token];
  float4 a = *(const float4*)(wte    + (size_t)id  * DD + c4);
  float4 b = *(const float4*)(wte_rf + (size_t)rid * DD + c4);
  float4 c = *(const float4*)(wpe    + (size_t)s   * DD + c4);
  float4 o;
  o.x = a.x + b.x + c.x;
  o.y = a.y + b.y + c.y;
  o.z = a.z + b.z + c.z;
  o.w = a.w + b.w + c.w;
  *(float4*)(h + (size_t)token * DD + c4) = o;
}

// ---------------- weight transpose+cast: W[K][N] fp32 -> Wt[N][K] bf16 ----------
__global__ __launch_bounds__(256) void transpose_cast(
    const float* __restrict__ W, bf16* __restrict__ Wt, int K, int N)
{
  __shared__ float tile[32][33];
  int n0 = blockIdx.x * 32, k0 = blockIdx.y * 32;
  int tx = threadIdx.x & 31, ty = threadIdx.x >> 5;
  #pragma unroll
  for (int i = 0; i < 4; ++i)
    tile[ty + 8 * i][tx] = W[(size_t)(k0 + ty + 8 * i) * N + n0 + tx];
  __syncthreads();
  #pragma unroll
  for (int i = 0; i < 4; ++i)
    Wt[(size_t)(n0 + ty + 8 * i) * K + k0 + tx] = __float2bfloat16(tile[tx][ty + 8 * i]);
}

// ---------------- V transpose: qkv V-block [s][d] bf16 -> vt[bh][d][s] bf16 ------
__global__ __launch_bounds__(256) void vtrans_kernel(
    const bf16* __restrict__ qkv, bf16* __restrict__ vt)
{
  __shared__ unsigned short tile[32][34];
  int bh = blockIdx.z, b = bh / HH, h = bh % HH;
  int s0 = blockIdx.x * 32, d0 = blockIdx.y * 32;
  int tx = threadIdx.x & 31, ty = threadIdx.x >> 5;
  const unsigned short* src =
      (const unsigned short*)qkv + (size_t)b * SS * D3 + 2 * DD + h * DHH;
  #pragma unroll
  for (int i = 0; i < 4; ++i)
    tile[ty + 8 * i][tx] = src[(size_t)(s0 + ty + 8 * i) * D3 + d0 + tx];
  __syncthreads();
  unsigned short* dst = (unsigned short*)vt + (size_t)bh * DHH * SS;
  #pragma unroll
  for (int i = 0; i < 4; ++i)
    dst[(size_t)(d0 + ty + 8 * i) * SS + s0 + tx] = tile[tx][ty + 8 * i];
}

// ---------------- LayerNorm: one block (192 threads) per row of 768 ----------------
template <typename OutT>
__global__ __launch_bounds__(192) void ln_kernel(
    const float* __restrict__ x, const float* __restrict__ g,
    const float* __restrict__ bb, OutT* __restrict__ y)
{
  __shared__ float red[2][3];
  int row = blockIdx.x;
  int t = threadIdx.x;
  const float* xr = x + (size_t)row * DD;
  float4 v = *(const float4*)(xr + t * 4);
  float s  = v.x + v.y + v.z + v.w;
  float sq = v.x * v.x + v.y * v.y + v.z * v.z + v.w * v.w;
  #pragma unroll
  for (int off = 32; off > 0; off >>= 1) {
    s  += __shfl_down(s, off);
    sq += __shfl_down(sq, off);
  }
  int wave = t >> 6, lane = t & 63;
  if (lane == 0) { red[0][wave] = s; red[1][wave] = sq; }
  __syncthreads();
  s  = red[0][0] + red[0][1] + red[0][2];
  sq = red[1][0] + red[1][1] + red[1][2];
  float mu   = s * (1.0f / DD);
  float var  = sq * (1.0f / DD) - mu * mu;
  float rstd = rsqrtf(var + LN_EPS);
  float4 gv = *(const float4*)(g  + t * 4);
  float4 bv = *(const float4*)(bb + t * 4);
  float o0 = (v.x - mu) * rstd * gv.x + bv.x;
  float o1 = (v.y - mu) * rstd * gv.y + bv.y;
  float o2 = (v.z - mu) * rstd * gv.z + bv.z;
  float o3 = (v.w - mu) * rstd * gv.w + bv.w;
  if constexpr (sizeof(OutT) == 4) {
    float4 o = {o0, o1, o2, o3};
    *(float4*)((float*)y + (size_t)row * DD + t * 4) = o;
  } else {
    ushort4 o = {f2bf_bits(o0), f2bf_bits(o1), f2bf_bits(o2), f2bf_bits(o3)};
    *(ushort4*)((unsigned short*)y + (size_t)row * DD + t * 4) = o;
  }
}

__device__ __forceinline__ float gelu_f(float x) {
  float x3 = x * x * x;
  return 0.5f * x * (1.0f + tanhf(0.7978845608028654f * (x + 0.044715f * x3)));
}

// ---------------- bf16 MFMA GEMM, templated tile, double-buffered ----------------
// C[M,N] = A[M,K] @ Wt[N,K]^T + bias.  4 waves arranged (BM/WM)x(BN/WN).
// MODE 0: +bias   MODE 1: +bias+R(fp32)   MODE 2: gelu(+bias)
template <int BM, int BN, int WM, int WN, int MODE, typename OutT>
__global__ __launch_bounds__(256) void gemm_bf16(
    const bf16* __restrict__ A,   // [M][K]
    const bf16* __restrict__ Wt,  // [N][K]
    const float* __restrict__ bias,
    const float* __restrict__ R,
    OutT* __restrict__ C, int M, int N, int K)
{
  constexpr int MR = WM / 16, NR = WN / 16;
  constexpr int WC = BN / WN;
  constexpr int ACH = BM * 4 / 256, BCH = BN * 4 / 256;
  constexpr int ABUF = BM * 64, BBUF = BN * 64;  // bytes per LDS buffer
  static_assert((BM / WM) * (BN / WN) == 4, "4 waves");
  __shared__ alignas(16) char AsB[2 * ABUF];
  __shared__ alignas(16) char BsB[2 * BBUF];
  const int t = threadIdx.x;
  const int lane = t & 63, wid = t >> 6;
  const int wr = wid / WC, wc = wid % WC;
  const int g = lane >> 4, l15 = lane & 15;

  const int nx = gridDim.x;
  const int nwg = nx * gridDim.y;
  const int bid0 = blockIdx.y * nx + blockIdx.x;
  const int bid = (bid0 & 7) * (nwg >> 3) + (bid0 >> 3);
  const int bm = (bid / nx) * BM, bn = (bid % nx) * BN;

  f32x4 acc[MR][NR] = {};

  const unsigned short* Ag[ACH];
  const unsigned short* Bg[BCH];
  #pragma unroll
  for (int i = 0; i < ACH; ++i) {
    int c = t + i * 256;
    Ag[i] = (const unsigned short*)A + (size_t)(bm + c % BM) * K + (c / BM) * 8;
  }
  #pragma unroll
  for (int i = 0; i < BCH; ++i) {
    int c = t + i * 256;
    Bg[i] = (const unsigned short*)Wt + (size_t)(bn + c % BN) * K + (c / BN) * 8;
  }

  auto stage = [&](int buf, int k0) {
    #pragma unroll
    for (int i = 0; i < ACH; ++i)
      gload_lds16(Ag[i] + k0, AsB + buf * ABUF + (t + i * 256) * 16);
    #pragma unroll
    for (int i = 0; i < BCH; ++i)
      gload_lds16(Bg[i] + k0, BsB + buf * BBUF + (t + i * 256) * 16);
  };

  const int abase = g * (BM * 16) + (wr * WM + l15) * 16;
  const int bbase = g * (BN * 16) + (wc * WN + l15) * 16;

  const int nt = K / 32;
  stage(0, 0);
  __syncthreads();
  for (int tk = 0; tk < nt; ++tk) {
    const int cur = tk & 1;
    if (tk + 1 < nt) stage(cur ^ 1, (tk + 1) * 32);
    bf16x8 a[MR], b[NR];
    #pragma unroll
    for (int m = 0; m < MR; ++m)
      a[m] = *(const bf16x8*)(AsB + cur * ABUF + abase + m * 256);
    #pragma unroll
    for (int n = 0; n < NR; ++n)
      b[n] = *(const bf16x8*)(BsB + cur * BBUF + bbase + n * 256);
    #pragma unroll
    for (int m = 0; m < MR; ++m)
      #pragma unroll
      for (int n = 0; n < NR; ++n)
        acc[m][n] = __builtin_amdgcn_mfma_f32_16x16x32_bf16(a[m], b[n], acc[m][n], 0, 0, 0);
    __syncthreads();
  }

  const int colg = l15, rowg = g * 4;
  #pragma unroll
  for (int m = 0; m < MR; ++m) {
    #pragma unroll
    for (int n = 0; n < NR; ++n) {
      int col = bn + wc * WN + n * 16 + colg;
      float bv = bias[col];
      #pragma unroll
      for (int r = 0; r < 4; ++r) {
        int row = bm + wr * WM + m * 16 + rowg + r;
        float v = acc[m][n][r] + bv;
        if constexpr (MODE == 1) v += R[(size_t)row * N + col];
        if constexpr (MODE == 2) v = gelu_f(v);
        if constexpr (sizeof(OutT) == 4) ((float*)C)[(size_t)row * N + col] = v;
        else ((bf16*)C)[(size_t)row * N + col] = __float2bfloat16(v);
      }
    }
  }
}

// ---------------- MFMA flash attention v2 ----------------------------------------
// Triangle-paired blocks (uniform work), register-rotated K/V prefetch, setprio.
// One wave = 16 q-rows. S^T = mfma(K,Q): softmax state at q=lane&15.
// O^T = mfma(V^T, P): accumulator cols q=lane&15 (rescale is lane-local).
__device__ __forceinline__ void attn_strip(
    const bf16* __restrict__ qbase, const bf16* __restrict__ kbase,
    const bf16* __restrict__ vbase, unsigned short (*pw)[40],
    bf16* __restrict__ o, int b, int h, int q0, int g, int l15)
{
  const int qg = q0 + l15;
  const int kvend = q0 + 16;
  bf16x8 qf0 = *(const bf16x8*)(qbase + (size_t)qg * D3 + g * 8);
  bf16x8 qf1 = *(const bf16x8*)(qbase + (size_t)qg * D3 + 32 + g * 8);
  f32x4 oa0 = {}, oa1 = {}, oa2 = {}, oa3 = {};
  float m = -1e30f, l = 0.f;

  // preload K,V for kv0 = 0
  const bf16* kr = kbase + (size_t)l15 * D3 + g * 8;
  bf16x8 k00 = *(const bf16x8*)(kr);
  bf16x8 k01 = *(const bf16x8*)(kr + 32);
  bf16x8 k10 = *(const bf16x8*)(kr + (size_t)16 * D3);
  bf16x8 k11 = *(const bf16x8*)(kr + (size_t)16 * D3 + 32);
  const bf16* vr = vbase + (size_t)l15 * SS + g * 8;
  bf16x8 v0 = *(const bf16x8*)(vr);
  bf16x8 v1 = *(const bf16x8*)(vr + (size_t)16 * SS);
  bf16x8 v2 = *(const bf16x8*)(vr + (size_t)32 * SS);
  bf16x8 v3 = *(const bf16x8*)(vr + (size_t)48 * SS);

  for (int kv0 = 0; kv0 < kvend; kv0 += 32) {
    // S^T tiles (rows kv, cols q)
    f32x4 s0 = {0.f, 0.f, 0.f, 0.f}, s1 = {0.f, 0.f, 0.f, 0.f};
    __builtin_amdgcn_s_setprio(1);
    s0 = __builtin_amdgcn_mfma_f32_16x16x32_bf16(k00, qf0, s0, 0, 0, 0);
    s0 = __builtin_amdgcn_mfma_f32_16x16x32_bf16(k01, qf1, s0, 0, 0, 0);
    s1 = __builtin_amdgcn_mfma_f32_16x16x32_bf16(k10, qf0, s1, 0, 0, 0);
    s1 = __builtin_amdgcn_mfma_f32_16x16x32_bf16(k11, qf1, s1, 0, 0, 0);
    __builtin_amdgcn_s_setprio(0);

    // prefetch next K (register rotate; hides under softmax+PV)
    const int kvn = (kv0 + 32 < kvend) ? kv0 + 32 : 0;
    const bf16* krn = kbase + (size_t)(kvn + l15) * D3 + g * 8;
    bf16x8 nk00 = *(const bf16x8*)(krn);
    bf16x8 nk01 = *(const bf16x8*)(krn + 32);
    bf16x8 nk10 = *(const bf16x8*)(krn + (size_t)16 * D3);
    bf16x8 nk11 = *(const bf16x8*)(krn + (size_t)16 * D3 + 32);

    // scale + causal mask; lane's kv = kv0 + tt*16 + 4g + r
    float sv[8];
    #pragma unroll
    for (int r = 0; r < 4; ++r) {
      int kva = kv0 + 4 * g + r, kvb = kv0 + 16 + 4 * g + r;
      sv[r]     = (kva > qg) ? -1e30f : s0[r] * 0.125f;
      sv[4 + r] = (kvb > qg) ? -1e30f : s1[r] * 0.125f;
    }
    // online softmax (reduce over kv: regs + lanes ^16 ^32)
    float pmax = sv[0];
    #pragma unroll
    for (int i = 1; i < 8; ++i) pmax = fmaxf(pmax, sv[i]);
    pmax = fmaxf(pmax, __shfl_xor(pmax, 16));
    pmax = fmaxf(pmax, __shfl_xor(pmax, 32));
    float mnew = fmaxf(m, pmax);
    float alpha = __expf(m - mnew);
    float rsum;
    ushort4 pA, pB;
    {
      float p0 = __expf(sv[0] - mnew), p1 = __expf(sv[1] - mnew);
      float p2 = __expf(sv[2] - mnew), p3 = __expf(sv[3] - mnew);
      float p4 = __expf(sv[4] - mnew), p5 = __expf(sv[5] - mnew);
      float p6 = __expf(sv[6] - mnew), p7 = __expf(sv[7] - mnew);
      rsum = ((p0 + p1) + (p2 + p3)) + ((p4 + p5) + (p6 + p7));
      pA.x = f2bf_bits(p0); pA.y = f2bf_bits(p1); pA.z = f2bf_bits(p2); pA.w = f2bf_bits(p3);
      pB.x = f2bf_bits(p4); pB.y = f2bf_bits(p5); pB.z = f2bf_bits(p6); pB.w = f2bf_bits(p7);
    }
    rsum += __shfl_xor(rsum, 16);
    rsum += __shfl_xor(rsum, 32);
    l = l * alpha + rsum; m = mnew;
    #pragma unroll
    for (int r = 0; r < 4; ++r) {
      oa0[r] *= alpha; oa1[r] *= alpha; oa2[r] *= alpha; oa3[r] *= alpha;
    }

    // P -> LDS (row q=l15), cross-lane redistribution for PV A... B-operand
    *(ushort4*)&pw[l15][4 * g]      = pA;
    *(ushort4*)&pw[l15][16 + 4 * g] = pB;
    asm volatile("s_waitcnt lgkmcnt(0)" ::: "memory");
    __builtin_amdgcn_sched_barrier(0);
    bf16x8 pf = *(const bf16x8*)&pw[l15][g * 8];

    __builtin_amdgcn_s_setprio(1);
    oa0 = __builtin_amdgcn_mfma_f32_16x16x32_bf16(v0, pf, oa0, 0, 0, 0);
    oa1 = __builtin_amdgcn_mfma_f32_16x16x32_bf16(v1, pf, oa1, 0, 0, 0);
    oa2 = __builtin_amdgcn_mfma_f32_16x16x32_bf16(v2, pf, oa2, 0, 0, 0);
    oa3 = __builtin_amdgcn_mfma_f32_16x16x32_bf16(v3, pf, oa3, 0, 0, 0);
    __builtin_amdgcn_s_setprio(0);

    // prefetch next V (rotate)
    const bf16* vrn = vbase + (size_t)l15 * SS + kvn + g * 8;
    v0 = *(const bf16x8*)(vrn);
    v1 = *(const bf16x8*)(vrn + (size_t)16 * SS);
    v2 = *(const bf16x8*)(vrn + (size_t)32 * SS);
    v3 = *(const bf16x8*)(vrn + (size_t)48 * SS);
    k00 = nk00; k01 = nk01; k10 = nk10; k11 = nk11;
  }

  float linv = 1.0f / l;
  unsigned short* ob = (unsigned short*)o + (size_t)(b * SS + qg) * DD + h * DHH;
  ushort4 w0 = {f2bf_bits(oa0[0] * linv), f2bf_bits(oa0[1] * linv),
                f2bf_bits(oa0[2] * linv), f2bf_bits(oa0[3] * linv)};
  ushort4 w1 = {f2bf_bits(oa1[0] * linv), f2bf_bits(oa1[1] * linv),
                f2bf_bits(oa1[2] * linv), f2bf_bits(oa1[3] * linv)};
  ushort4 w2 = {f2bf_bits(oa2[0] * linv), f2bf_bits(oa2[1] * linv),
                f2bf_bits(oa2[2] * linv), f2bf_bits(oa2[3] * linv)};
  ushort4 w3 = {f2bf_bits(oa3[0] * linv), f2bf_bits(oa3[1] * linv),
                f2bf_bits(oa3[2] * linv), f2bf_bits(oa3[3] * linv)};
  *(ushort4*)(ob + 0 * 16 + 4 * g) = w0;
  *(ushort4*)(ob + 1 * 16 + 4 * g) = w1;
  *(ushort4*)(ob + 2 * 16 + 4 * g) = w2;
  *(ushort4*)(ob + 3 * 16 + 4 * g) = w3;
}

__global__ __launch_bounds__(256) void attn_mfma(
    const bf16* __restrict__ qkv,  // [B*S][3D] bf16
    const bf16* __restrict__ vt,   // [B*H][64][S] bf16
    bf16* __restrict__ o)          // [B*S][D] bf16
{
  __shared__ unsigned short plds[4][16][40];
  const int bid = blockIdx.x;                   // 384 = 48 bh * 8 pairs
  const int swz = (bid & 7) * 48 + (bid >> 3);  // XCD-contiguous, bh-major
  const int bh = swz >> 3, p = swz & 7;
  const int b = bh / HH, h = bh % HH;
  const int w = threadIdx.x >> 6, lane = threadIdx.x & 63;
  const int g = lane >> 4, l15 = lane & 15;

  const bf16* qbase = qkv + (size_t)b * SS * D3 + h * DHH;
  const bf16* kbase = qbase + DD;
  const bf16* vbase = vt + (size_t)bh * DHH * SS;

  // triangle pairing: qtiles p and 15-p -> uniform per-wave work
  attn_strip(qbase, kbase, vbase, plds[w], o, b, h, p * 64 + w * 16, g, l15);
  attn_strip(qbase, kbase, vbase, plds[w], o, b, h, (15 - p) * 64 + w * 16, g, l15);
}

extern "C" void kernel_launch(void* const* d_in, const int* in_sizes, int n_in,
                              void* d_out, int out_size, void* d_ws, size_t ws_size,
                              hipStream_t stream)
{
  (void)in_sizes; (void)n_in; (void)out_size; (void)ws_size;
  const int*   ids    = (const int*)d_in[0];
  const int*   rfids  = (const int*)d_in[1];
  const float* wte    = (const float*)d_in[2];
  const float* wte_rf = (const float*)d_in[3];
  const float* wpe    = (const float*)d_in[4];
  const float* ln1_g  = (const float*)d_in[5];
  const float* ln1_b  = (const float*)d_in[6];
  const float* attn_w = (const float*)d_in[7];
  const float* attn_b = (const float*)d_in[8];
  const float* proj_w = (const float*)d_in[9];
  const float* proj_b = (const float*)d_in[10];
  const float* ln2_g  = (const float*)d_in[11];
  const float* ln2_b  = (const float*)d_in[12];
  const float* fc_w   = (const float*)d_in[13];
  const float* fc_b   = (const float*)d_in[14];
  const float* fc2_w  = (const float*)d_in[15];
  const float* fc2_b  = (const float*)d_in[16];
  const float* lnf_g  = (const float*)d_in[17];
  const float* lnf_b  = (const float*)d_in[18];

  const int T = BB * SS;  // 4096 tokens
  const size_t TD = (size_t)T * DD;
  // workspace (58.2 MB): ff aliases [qkvb|vt] (3D + D = DF); a/att share.
  float* h    = (float*)d_ws;                   // [T][D] fp32        12.6 MB
  bf16*  qkvb = (bf16*)(h + TD);                // [T][3D] bf16       18.9 MB
  bf16*  vtb  = qkvb + (size_t)T * D3;          // [BH][64][S] bf16    6.3 MB
  bf16*  ff   = qkvb;                           // [T][DF] bf16 (alias)
  bf16*  a    = vtb + TD;                       // [T][D] bf16         6.3 MB
  bf16*  att  = a;                              // alias
  bf16*  awt  = a + TD;                         // [3D][D]             3.5 MB
  bf16*  pwt  = awt + (size_t)D3 * DD;          // [D][D]              1.2 MB
  bf16*  fwt  = pwt + (size_t)DD * DD;          // [DF][D]             4.7 MB
  bf16*  f2wt = fwt + (size_t)DFF * DD;         // [D][DF]             4.7 MB

  embed_kernel<<<dim3((T * DD / 4) / 256), 256, 0, stream>>>(ids, rfids, wte, wte_rf, wpe, h);

  for (int l = 0; l < NLAYER; ++l) {
    transpose_cast<<<dim3(D3 / 32,  DD / 32),  256, 0, stream>>>(attn_w + (size_t)l * DD * D3,  awt,  DD,  D3);
    transpose_cast<<<dim3(DD / 32,  DD / 32),  256, 0, stream>>>(proj_w + (size_t)l * DD * DD,  pwt,  DD,  DD);
    transpose_cast<<<dim3(DFF / 32, DD / 32),  256, 0, stream>>>(fc_w   + (size_t)l * DD * DFF, fwt,  DD,  DFF);
    transpose_cast<<<dim3(DD / 32,  DFF / 32), 256, 0, stream>>>(fc2_w  + (size_t)l * DFF * DD, f2wt, DFF, DD);

    ln_kernel<bf16><<<T, 192, 0, stream>>>(h, ln1_g + (size_t)l * DD, ln1_b + (size_t)l * DD, a);
    gemm_bf16<128, 128, 64, 64, 0, bf16><<<dim3(D3 / 128, T / 128), 256, 0, stream>>>(
        a, awt, attn_b + (size_t)l * D3, nullptr, qkvb, T, D3, DD);
    vtrans_kernel<<<dim3(SS / 32, DHH / 32, BB * HH), 256, 0, stream>>>(qkvb, vtb);
    attn_mfma<<<BB * HH * (SS / 64) / 2, 256, 0, stream>>>(qkvb, vtb, att);
    gemm_bf16<64, 128, 32, 64, 1, float><<<dim3(DD / 128, T / 64), 256, 0, stream>>>(
        att, pwt, proj_b + (size_t)l * DD, h, h, T, DD, DD);
    ln_kernel<bf16><<<T, 192, 0, stream>>>(h, ln2_g + (size_t)l * DD, ln2_b + (size_t)l * DD, a);
    gemm_bf16<128, 128, 64, 64, 2, bf16><<<dim3(DFF / 128, T / 128), 256, 0, stream>>>(
        a, fwt, fc_b + (size_t)l * DFF, nullptr, ff, T, DFF, DD);
    gemm_bf16<64, 128, 32, 64, 1, float><<<dim3(DD / 128, T / 64), 256, 0, stream>>>(
        ff, f2wt, fc2_b + (size_t)l * DD, h, h, T, DD, DFF);
  }
  ln_kernel<float><<<T, 192, 0, stream>>>(h, lnf_g, lnf_b, (float*)d_out);
}